// Round 12
// baseline (2296.383 us; speedup 1.0000x reference)
//
#include <hip/hip_runtime.h>

// ---------------- problem constants ----------------
#define B_    2
#define S_    2048
#define HID_  3584
#define NH_   16
#define NKV_  8
#define HD_   256
#define DQ_   (NH_ * HD_)    // 4096
#define DKV_  (NKV_ * HD_)   // 2048

static constexpr float SCALE_ = 0.0625f;   // 256^-0.5

typedef __bf16 bf16_t;
typedef __bf16 bf16x8 __attribute__((ext_vector_type(8)));
typedef __bf16 bf16x4 __attribute__((ext_vector_type(4)));
typedef float  f32x4  __attribute__((ext_vector_type(4)));

// ---------------- f32 -> bf16 convert ----------------
__global__ __launch_bounds__(256) void cvt_kernel(const float* __restrict__ in,
                                                  bf16_t* __restrict__ out, int n4) {
  int i = blockIdx.x * 256 + threadIdx.x;
  if (i < n4) {
    float4 v = ((const float4*)in)[i];
    bf16x4 o;
    o[0] = (bf16_t)v.x; o[1] = (bf16_t)v.y; o[2] = (bf16_t)v.z; o[3] = (bf16_t)v.w;
    ((bf16x4*)out)[i] = o;
  }
}

// ---------------- async global->LDS, 16B per lane ----------------
__device__ inline void gload_lds16(const bf16_t* g, bf16_t* l) {
  __builtin_amdgcn_global_load_lds(
      (const __attribute__((address_space(1))) void*)g,
      (__attribute__((address_space(3))) void*)l, 16, 0, 0);
}

// ---------------- GEMM (m97 structure): C[m][n] = sum_k A[m][k]*Bt[n][k], both bf16 ----------------
// MODE 0: OUT f32, plain row-major [M][N]          (o-proj -> d_out)
// MODE 1: OUT bf16, relayout to (B, nh, S, HD)     (Q, K projections)
// MODE 2: OUT bf16, transpose to (B, NKV, HD, S)   (V projection)
template<int MODE>
__global__ __launch_bounds__(256) void gemm_lds(const bf16_t* __restrict__ A,
                                                const bf16_t* __restrict__ Bt,
                                                void* __restrict__ outv,
                                                int M, int N, int K, int nh) {
  __shared__ __align__(16) bf16_t As[128 * 32];
  __shared__ __align__(16) bf16_t Bs[128 * 32];
  const int t = threadIdx.x;
  const int lane = t & 63, wv = t >> 6;
  const int wr = wv >> 1, wc = wv & 1;
  const int lr = lane & 15, lg = lane >> 4;
  const size_t m0 = (size_t)blockIdx.y * 128, n0 = (size_t)blockIdx.x * 128;

  const int srow = wv * 32 + (lane >> 2);
  const int scol = (lane & 3) * 8;
  const bf16_t* ga0 = A  + (m0 + srow) * (size_t)K + scol;
  const bf16_t* gb0 = Bt + (n0 + srow) * (size_t)K + scol;
  bf16_t* la0 = &As[wv * 1024];        // wave-uniform LDS bases
  bf16_t* la1 = &As[wv * 1024 + 512];
  bf16_t* lb0 = &Bs[wv * 1024];
  bf16_t* lb1 = &Bs[wv * 1024 + 512];
  const size_t k16 = 16 * (size_t)K;

  f32x4 acc[4][4] = {};
  for (int k0 = 0; k0 < K; k0 += 32) {
    __syncthreads();
    gload_lds16(ga0 + k0,       la0);
    gload_lds16(ga0 + k16 + k0, la1);
    gload_lds16(gb0 + k0,       lb0);
    gload_lds16(gb0 + k16 + k0, lb1);
    __syncthreads();

    bf16x8 af[4], bfr[4];
#pragma unroll
    for (int i = 0; i < 4; ++i) af[i]  = *(const bf16x8*)&As[(wr * 64 + i * 16 + lr) * 32 + lg * 8];
#pragma unroll
    for (int j = 0; j < 4; ++j) bfr[j] = *(const bf16x8*)&Bs[(wc * 64 + j * 16 + lr) * 32 + lg * 8];
#pragma unroll
    for (int i = 0; i < 4; ++i)
#pragma unroll
      for (int j = 0; j < 4; ++j)
        acc[i][j] = __builtin_amdgcn_mfma_f32_16x16x32_bf16(af[i], bfr[j], acc[i][j], 0, 0, 0);
  }
#pragma unroll
  for (int i = 0; i < 4; ++i)
#pragma unroll
    for (int j = 0; j < 4; ++j) {
      const int row0 = (int)m0 + wr * 64 + i * 16 + lg * 4;
      const int col  = (int)n0 + wc * 64 + j * 16 + lr;
#pragma unroll
      for (int r = 0; r < 4; ++r) {
        const int row = row0 + r;
        if (MODE == 0) {
          ((float*)outv)[(size_t)row * N + col] = acc[i][j][r];
        } else {
          bf16_t* out = (bf16_t*)outv;
          const bf16_t val = (bf16_t)acc[i][j][r];
          const int b = row >> 11, s = row & (S_ - 1);
          const int h = col >> 8,  hd = col & (HD_ - 1);
          if (MODE == 1) out[((size_t)(b * nh + h) * S_ + s) * HD_ + hd] = val;
          else           out[((size_t)(b * NKV_ + h) * HD_ + hd) * S_ + s] = val;
        }
      }
    }
}

// ---------------- fused RMSNorm + RoPE (in place), (b, s, h) block order ----------------
// rownorm (non-null): per-row |x|^2 after norm, before bf16 rounding (RoPE preserves norm)
template<int LOGNH>
__global__ __launch_bounds__(256) void normrope_kernel(bf16_t* __restrict__ x,
                                                       const float* __restrict__ w,
                                                       const float* __restrict__ cosb,
                                                       const float* __restrict__ sinb,
                                                       float* __restrict__ rownorm) {
  const int gid  = blockIdx.x * 4 + (threadIdx.x >> 6);  // (b, s, h) order: h innermost
  const int lane = threadIdx.x & 63;
  const int nh = 1 << LOGNH;
  const int h  = gid & (nh - 1);
  const int bs = gid >> LOGNH;                 // b*S + s
  const int b  = bs >> 11, s = bs & (S_ - 1);
  const int rowi = (b * nh + h) * S_ + s;

  bf16_t* ptr = x + (size_t)rowi * HD_ + lane * 4;
  bf16x4 xv = *(const bf16x4*)ptr;
  float v0 = (float)xv[0], v1 = (float)xv[1], v2 = (float)xv[2], v3 = (float)xv[3];
  float ss = v0 * v0 + v1 * v1 + v2 * v2 + v3 * v3;
#pragma unroll
  for (int off = 1; off < 64; off <<= 1) ss += __shfl_xor(ss, off);
  float r = rsqrtf(ss * (1.0f / HD_) + 1e-6f);

  float4 wv = *(const float4*)(w + lane * 4);
  float x0 = v0 * r * (1.0f + wv.x);
  float x1 = v1 * r * (1.0f + wv.y);
  float x2 = v2 * r * (1.0f + wv.z);
  float x3 = v3 * r * (1.0f + wv.w);

  if (rownorm != nullptr) {
    float s2 = x0 * x0 + x1 * x1 + x2 * x2 + x3 * x3;
#pragma unroll
    for (int off = 1; off < 64; off <<= 1) s2 += __shfl_xor(s2, off);
    if (lane == 0) rownorm[rowi] = s2;
  }

  float p0 = __shfl_xor(x0, 32);
  float p1 = __shfl_xor(x1, 32);
  float p2 = __shfl_xor(x2, 32);
  float p3 = __shfl_xor(x3, 32);
  float sgn = (lane < 32) ? -1.0f : 1.0f;

  float4 c  = *(const float4*)(cosb + (size_t)bs * HD_ + lane * 4);
  float4 sn = *(const float4*)(sinb + (size_t)bs * HD_ + lane * 4);
  bf16x4 o;
  o[0] = (bf16_t)(x0 * c.x + sgn * p0 * sn.x);
  o[1] = (bf16_t)(x1 * c.y + sgn * p1 * sn.y);
  o[2] = (bf16_t)(x2 * c.z + sgn * p2 * sn.z);
  o[3] = (bf16_t)(x3 * c.w + sgn * p3 * sn.w);
  *(bf16x4*)ptr = o;
}

// ---------------- per-(b,kv-head) max of knorm ----------------
__global__ __launch_bounds__(256) void kmax_reduce_kernel(const float* __restrict__ knorm,
                                                          float* __restrict__ km) {
  __shared__ float red[4];
  const int t = threadIdx.x;
  const float* src = knorm + (size_t)blockIdx.x * S_;
  float m = 0.0f;
  for (int i = t; i < S_; i += 256) m = fmaxf(m, src[i]);
#pragma unroll
  for (int off = 1; off < 64; off <<= 1) m = fmaxf(m, __shfl_xor(m, off));
  if ((t & 63) == 0) red[t >> 6] = m;
  __syncthreads();
  if (t == 0) km[blockIdx.x] = fmaxf(fmaxf(red[0], red[1]), fmaxf(red[2], red[3]));
}

// ---------------- single-pass flash attention (store-free hot loop) ----------------
// XCD-pinned 1-D grid; bound-based softmax via qnorm/kmax; outputs ctx + linv only.
__global__ __launch_bounds__(256, 4) void attn1p_kernel(const bf16_t* __restrict__ qb,
                                                        const bf16_t* __restrict__ kb,
                                                        const bf16_t* __restrict__ vt,
                                                        const float* __restrict__ qnorm,
                                                        const float* __restrict__ kmaxbuf,
                                                        float* __restrict__ linv,
                                                        bf16_t* __restrict__ ctx) {
  __shared__ __align__(16) bf16_t Ks[32][264];      // +8 pad
  __shared__ __align__(16) bf16_t Vs[256][36];      // d-major, +4 pad
  __shared__ __align__(16) bf16_t p_lds[4][16][36];

  const int t = threadIdx.x, w = t >> 6, lane = t & 63;
  const int lr = lane & 15, lg = lane >> 4, rloc = lg * 4;

  // XCD-pinned decode: all 64 blocks of one (b,kvh) group land on one XCD (wgid%8 heuristic)
  const int wgid = blockIdx.x;
  const int g    = ((wgid >> 9) << 3) | (wgid & 7);   // (b*NKV + kvh) group, 0..15
  const int idx  = (wgid >> 3) & 63;
  const int b    = g >> 3, kvh = g & 7;
  const int h    = kvh * 2 + (idx >> 5);
  const int qbucket = idx & 31;
  const int bh   = b * NH_ + h;
  const int q0b  = qbucket * 64;
  const int q0   = q0b + w * 16;

  const bf16_t* qptr = qb + ((size_t)bh * S_ + q0 + lr) * HD_ + lg * 8;
  bf16x8 qf[8];
#pragma unroll
  for (int c = 0; c < 8; ++c) qf[c] = *(const bf16x8*)(qptr + c * 32);

  const float kmax2 = kmaxbuf[b * NKV_ + kvh];
  float mb[4];
#pragma unroll
  for (int r = 0; r < 4; ++r)
    mb[r] = SCALE_ * sqrtf(qnorm[(size_t)bh * S_ + q0 + rloc + r] * kmax2) + 1.0f;

  float l[4] = {0.f, 0.f, 0.f, 0.f};
  f32x4 oacc[16] = {};
  const int nkt = (q0b + 64) >> 5;
  const bf16_t* kgb = kb + (size_t)(b * NKV_ + kvh) * S_ * HD_;
  const bf16_t* vgb = vt + (size_t)(b * NKV_ + kvh) * HD_ * S_;

  const int s_st = t >> 3, c_st = (t & 7) * 32;   // K staging
  const int vrow = t >> 2, vcol = (t & 3) * 8;    // V staging (16B/lane)

  for (int kt = 0; kt < nkt; ++kt) {
    const int colb = kt * 32;
    __syncthreads();
    {
      const bf16_t* src = kgb + (size_t)(colb + s_st) * HD_ + c_st;
      bf16x8 k0 = *(const bf16x8*)(src);
      bf16x8 k1 = *(const bf16x8*)(src + 8);
      bf16x8 k2 = *(const bf16x8*)(src + 16);
      bf16x8 k3 = *(const bf16x8*)(src + 24);
      *(bf16x8*)&Ks[s_st][c_st]      = k0;
      *(bf16x8*)&Ks[s_st][c_st + 8]  = k1;
      *(bf16x8*)&Ks[s_st][c_st + 16] = k2;
      *(bf16x8*)&Ks[s_st][c_st + 24] = k3;
    }
#pragma unroll
    for (int i = 0; i < 4; ++i) {
      const int d = vrow + i * 64;
      bf16x8 vv = *(const bf16x8*)(vgb + (size_t)d * S_ + colb + vcol);
      *(bf16x8*)&Vs[d][vcol] = vv;
    }
    __syncthreads();

    if (colb <= q0 + 15) {
      f32x4 s0 = {0.f, 0.f, 0.f, 0.f}, s1 = {0.f, 0.f, 0.f, 0.f};
#pragma unroll
      for (int c = 0; c < 8; ++c) {
        bf16x8 k0 = *(const bf16x8*)&Ks[lr][c * 32 + lg * 8];
        bf16x8 k1 = *(const bf16x8*)&Ks[16 + lr][c * 32 + lg * 8];
        s0 = __builtin_amdgcn_mfma_f32_16x16x32_bf16(qf[c], k0, s0, 0, 0, 0);
        s1 = __builtin_amdgcn_mfma_f32_16x16x32_bf16(qf[c], k1, s1, 0, 0, 0);
      }
      const int col0 = colb + lr, col1 = col0 + 16;
#pragma unroll
      for (int r = 0; r < 4; ++r) {
        const int row = q0 + rloc + r;
        const float pa = (col0 <= row) ? __expf(s0[r] * SCALE_ - mb[r]) : 0.0f;
        const float pb = (col1 <= row) ? __expf(s1[r] * SCALE_ - mb[r]) : 0.0f;
        l[r] += pa + pb;
        p_lds[w][rloc + r][lr]      = (bf16_t)pa;
        p_lds[w][rloc + r][lr + 16] = (bf16_t)pb;
      }
      bf16x8 pf = *(const bf16x8*)&p_lds[w][lr][lg * 8];
#pragma unroll
      for (int df = 0; df < 16; ++df) {
        bf16x8 vf = *(const bf16x8*)&Vs[df * 16 + lr][lg * 8];
        oacc[df] = __builtin_amdgcn_mfma_f32_16x16x32_bf16(pf, vf, oacc[df], 0, 0, 0);
      }
    }
  }
#pragma unroll
  for (int r = 0; r < 4; ++r) {
    l[r] += __shfl_xor(l[r], 1);
    l[r] += __shfl_xor(l[r], 2);
    l[r] += __shfl_xor(l[r], 4);
    l[r] += __shfl_xor(l[r], 8);
  }
  float invl[4];
#pragma unroll
  for (int r = 0; r < 4; ++r) invl[r] = 1.0f / l[r];

  bf16_t* cp = ctx + ((size_t)b * S_ + q0) * DQ_ + h * HD_;
#pragma unroll
  for (int df = 0; df < 16; ++df)
#pragma unroll
    for (int r = 0; r < 4; ++r)
      cp[(size_t)(rloc + r) * DQ_ + df * 16 + lr] = (bf16_t)(oacc[df][r] * invl[r]);

  if (lr == 0) {
#pragma unroll
    for (int r = 0; r < 4; ++r) linv[(size_t)bh * S_ + q0 + rloc + r] = invl[r];
  }
}

// ---------------- weights generation: recompute QK^T, write normalized f32 coalesced ----------------
// grid (ki, qi, bh): 128x128 tile per block; ki>qi -> pure zero stores.
__global__ __launch_bounds__(256) void wgen_kernel(const bf16_t* __restrict__ qb,
                                                   const bf16_t* __restrict__ kb,
                                                   const float* __restrict__ qnorm,
                                                   const float* __restrict__ kmaxbuf,
                                                   const float* __restrict__ linv,
                                                   float* __restrict__ wout) {
  const int bh = blockIdx.z, b = bh >> 4, h = bh & 15, kvh = h >> 1;
  const int qi = blockIdx.y, ki = blockIdx.x;
  const int q0 = qi * 128, k0 = ki * 128;
  const int t = threadIdx.x;
  float* wbase = wout + ((size_t)bh * S_ + q0) * S_ + k0;

  if (ki > qi) {   // zero tile: 128x128 f32, coalesced stores only
    const f32x4 z = {0.f, 0.f, 0.f, 0.f};
#pragma unroll
    for (int p = 0; p < 16; ++p)
      *(f32x4*)(wbase + (size_t)(p * 8 + (t >> 5)) * S_ + (t & 31) * 4) = z;
    return;
  }

  __shared__ __align__(16) bf16_t As[128 * 32];
  __shared__ __align__(16) bf16_t Bs[128 * 32];
  __shared__ float Ts[128][36];   // 32-col transpose slab (+4 pad)

  const int lane = t & 63, wv = t >> 6;
  const int wr = wv >> 1, wc = wv & 1;
  const int lr = lane & 15, lg = lane >> 4;

  const int srow = wv * 32 + (lane >> 2);
  const int scol = (lane & 3) * 8;
  const bf16_t* ga0 = qb + ((size_t)bh * S_ + q0 + srow) * HD_ + scol;
  const bf16_t* gb0 = kb + ((size_t)(b * NKV_ + kvh) * S_ + k0 + srow) * HD_ + scol;
  bf16_t* la0 = &As[wv * 1024];
  bf16_t* la1 = &As[wv * 1024 + 512];
  bf16_t* lb0 = &Bs[wv * 1024];
  bf16_t* lb1 = &Bs[wv * 1024 + 512];
  const size_t k16 = 16 * (size_t)HD_;

  f32x4 acc[4][4] = {};
  for (int kk = 0; kk < HD_; kk += 32) {
    __syncthreads();
    gload_lds16(ga0 + kk,       la0);
    gload_lds16(ga0 + k16 + kk, la1);
    gload_lds16(gb0 + kk,       lb0);
    gload_lds16(gb0 + k16 + kk, lb1);
    __syncthreads();

    bf16x8 af[4], bfr[4];
#pragma unroll
    for (int i = 0; i < 4; ++i) af[i]  = *(const bf16x8*)&As[(wr * 64 + i * 16 + lr) * 32 + lg * 8];
#pragma unroll
    for (int j = 0; j < 4; ++j) bfr[j] = *(const bf16x8*)&Bs[(wc * 64 + j * 16 + lr) * 32 + lg * 8];
#pragma unroll
    for (int i = 0; i < 4; ++i)
#pragma unroll
      for (int j = 0; j < 4; ++j)
        acc[i][j] = __builtin_amdgcn_mfma_f32_16x16x32_bf16(af[i], bfr[j], acc[i][j], 0, 0, 0);
  }

  const float kmax2 = kmaxbuf[b * NKV_ + kvh];
  const bool full = (ki < qi);    // strictly-below-diagonal tile: no mask needed

  // 4 slabs of 32 cols: wave wc==s>>1 fills from acc j = (s&1)*2 + {0,1}; all store coalesced
#pragma unroll 1
  for (int s = 0; s < 4; ++s) {
    __syncthreads();
    if (wc == (s >> 1)) {
      const int j0 = (s & 1) * 2;
#pragma unroll
      for (int jj = 0; jj < 2; ++jj) {
#pragma unroll
        for (int i = 0; i < 4; ++i) {
#pragma unroll
          for (int r = 0; r < 4; ++r) {
            const int lrow = wr * 64 + i * 16 + lg * 4 + r;
            const int grow = q0 + lrow;
            const int gcol = k0 + s * 32 + jj * 16 + lr;
            float val = 0.0f;
            if (full || gcol <= grow) {
              const float mbv = SCALE_ * sqrtf(qnorm[(size_t)bh * S_ + grow] * kmax2) + 1.0f;
              val = __expf(acc[i][j0 + jj][r] * SCALE_ - mbv) * linv[(size_t)bh * S_ + grow];
            }
            Ts[lrow][jj * 16 + lr] = val;
          }
        }
      }
    }
    __syncthreads();
#pragma unroll
    for (int p = 0; p < 4; ++p) {
      const int row = p * 32 + (t >> 3);
      const int c4  = (t & 7) * 4;
      f32x4 v = {Ts[row][c4], Ts[row][c4 + 1], Ts[row][c4 + 2], Ts[row][c4 + 3]};
      *(f32x4*)(wbase + (size_t)row * S_ + s * 32 + c4) = v;
    }
  }
}

// ---------------- launch ----------------
extern "C" void kernel_launch(void* const* d_in, const int* in_sizes, int n_in,
                              void* d_out, int out_size, void* d_ws, size_t ws_size,
                              hipStream_t stream) {
  const float* hs   = (const float*)d_in[0];
  const float* cosb = (const float*)d_in[1];
  const float* sinb = (const float*)d_in[2];
  // d_in[3] attention_mask: recomputed causally in-kernel
  const float* Wq = (const float*)d_in[4];
  const float* Wk = (const float*)d_in[5];
  const float* Wv = (const float*)d_in[6];
  const float* Wo = (const float*)d_in[7];
  const float* qw = (const float*)d_in[8];
  const float* kw = (const float*)d_in[9];

  char* ws = (char*)d_ws;
  bf16_t* qb    = (bf16_t*)(ws + 0);            // 33,554,432  (B,NH,S,HD)
  bf16_t* kb    = (bf16_t*)(ws + 33554432);     // 16,777,216  (B,NKV,S,HD)
  bf16_t* vt    = (bf16_t*)(ws + 50331648);     // 16,777,216  (B,NKV,HD,S)
  bf16_t* ctx   = (bf16_t*)(ws + 67108864);     // 33,554,432  (B,S,NH*HD)
  float*  linv  = (float*)(ws + 100663296);     //    262,144
  float*  knorm = (float*)(ws + 100925440);     //    131,072
  float*  km    = (float*)(ws + 101056512);     //        128
  bf16_t* hsb   = (bf16_t*)(ws + 101056640);    // 29,360,128
  bf16_t* wqb   = (bf16_t*)(ws + 130416768);    // 29,360,128
  bf16_t* wkb   = (bf16_t*)(ws + 159776896);    // 14,680,064
  bf16_t* wvb   = (bf16_t*)(ws + 174456960);    // 14,680,064
  bf16_t* wob   = (bf16_t*)(ws + 189137024);    // 29,360,128
  float*  qnorm = (float*)(ws + 218497152);     //    262,144  -> total 218,759,296

  float* out      = (float*)d_out;
  float* attn_out = out;                            // (B,S,HID) f32
  float* weights  = out + (size_t)B_ * S_ * HID_;   // (B,NH,S,S) f32

  const int M = B_ * S_;  // 4096

  // 0) one-shot bf16 conversion of activations + weights
  cvt_kernel<<<14336, 256, 0, stream>>>(hs, hsb, (B_ * S_ * HID_) / 4);
  cvt_kernel<<<14336, 256, 0, stream>>>(Wq, wqb, (DQ_ * HID_) / 4);
  cvt_kernel<<<7168,  256, 0, stream>>>(Wk, wkb, (DKV_ * HID_) / 4);
  cvt_kernel<<<7168,  256, 0, stream>>>(Wv, wvb, (DKV_ * HID_) / 4);
  cvt_kernel<<<14336, 256, 0, stream>>>(Wo, wob, (HID_ * DQ_) / 4);

  // 1) projections (bf16 x bf16, global_load_lds staging)
  gemm_lds<1><<<dim3(DQ_ / 128, M / 128), 256, 0, stream>>>(hsb, wqb, qb, M, DQ_, HID_, NH_);
  gemm_lds<1><<<dim3(DKV_ / 128, M / 128), 256, 0, stream>>>(hsb, wkb, kb, M, DKV_, HID_, NKV_);
  gemm_lds<2><<<dim3(DKV_ / 128, M / 128), 256, 0, stream>>>(hsb, wvb, vt, M, DKV_, HID_, NKV_);

  // 2) norm + rope (in place); both passes store per-row |x|^2
  normrope_kernel<4><<<(B_ * S_ * NH_) / 4, 256, 0, stream>>>(qb, qw, cosb, sinb, qnorm);
  normrope_kernel<3><<<(B_ * S_ * NKV_) / 4, 256, 0, stream>>>(kb, kw, cosb, sinb, knorm);
  kmax_reduce_kernel<<<B_ * NKV_, 256, 0, stream>>>(knorm, km);

  // 3) flash attention (store-free hot loop), XCD-pinned grid
  attn1p_kernel<<<(S_ / 64) * (B_ * NH_), 256, 0, stream>>>(qb, kb, vt, qnorm, km, linv, ctx);

  // 4) weights: recompute QK^T + normalize + coalesced f32 stores (replaces wscale)
  wgen_kernel<<<dim3(S_ / 128, S_ / 128, B_ * NH_), 256, 0, stream>>>(qb, kb, qnorm, km, linv, weights);

  // 5) output projection -> d_out (f32)
  gemm_lds<0><<<dim3(HID_ / 128, M / 128), 256, 0, stream>>>(ctx, wob, attn_out, M, HID_, DQ_, 0);
}

// Round 13
// 1048.590 us; speedup vs baseline: 2.1900x; 2.1900x over previous
//
#include <hip/hip_runtime.h>

// ---------------- problem constants ----------------
#define B_    2
#define S_    2048
#define HID_  3584
#define NH_   16
#define NKV_  8
#define HD_   256
#define DQ_   (NH_ * HD_)    // 4096
#define DKV_  (NKV_ * HD_)   // 2048

static constexpr float SCALE_ = 0.0625f;   // 256^-0.5

typedef __bf16 bf16_t;
typedef __bf16 bf16x8 __attribute__((ext_vector_type(8)));
typedef __bf16 bf16x4 __attribute__((ext_vector_type(4)));
typedef float  f32x4  __attribute__((ext_vector_type(4)));

// ---------------- f32 -> bf16 convert ----------------
__global__ __launch_bounds__(256) void cvt_kernel(const float* __restrict__ in,
                                                  bf16_t* __restrict__ out, int n4) {
  int i = blockIdx.x * 256 + threadIdx.x;
  if (i < n4) {
    float4 v = ((const float4*)in)[i];
    bf16x4 o;
    o[0] = (bf16_t)v.x; o[1] = (bf16_t)v.y; o[2] = (bf16_t)v.z; o[3] = (bf16_t)v.w;
    ((bf16x4*)out)[i] = o;
  }
}

// ---------------- async global->LDS, 16B per lane ----------------
__device__ inline void gload_lds16(const bf16_t* g, bf16_t* l) {
  __builtin_amdgcn_global_load_lds(
      (const __attribute__((address_space(1))) void*)g,
      (__attribute__((address_space(3))) void*)l, 16, 0, 0);
}

// ---------------- GEMM (m97 structure): C[m][n] = sum_k A[m][k]*Bt[n][k], both bf16 ----------------
// MODE 0: OUT f32, plain row-major [M][N]          (o-proj -> d_out)
// MODE 1: OUT bf16, relayout to (B, nh, S, HD)     (Q, K projections)
// MODE 2: OUT bf16, transpose to (B, NKV, HD, S)   (V projection)
template<int MODE>
__global__ __launch_bounds__(256) void gemm_lds(const bf16_t* __restrict__ A,
                                                const bf16_t* __restrict__ Bt,
                                                void* __restrict__ outv,
                                                int M, int N, int K, int nh) {
  __shared__ __align__(16) bf16_t As[128 * 32];
  __shared__ __align__(16) bf16_t Bs[128 * 32];
  const int t = threadIdx.x;
  const int lane = t & 63, wv = t >> 6;
  const int wr = wv >> 1, wc = wv & 1;
  const int lr = lane & 15, lg = lane >> 4;
  const size_t m0 = (size_t)blockIdx.y * 128, n0 = (size_t)blockIdx.x * 128;

  const int srow = wv * 32 + (lane >> 2);
  const int scol = (lane & 3) * 8;
  const bf16_t* ga0 = A  + (m0 + srow) * (size_t)K + scol;
  const bf16_t* gb0 = Bt + (n0 + srow) * (size_t)K + scol;
  bf16_t* la0 = &As[wv * 1024];        // wave-uniform LDS bases
  bf16_t* la1 = &As[wv * 1024 + 512];
  bf16_t* lb0 = &Bs[wv * 1024];
  bf16_t* lb1 = &Bs[wv * 1024 + 512];
  const size_t k16 = 16 * (size_t)K;

  f32x4 acc[4][4] = {};
  for (int k0 = 0; k0 < K; k0 += 32) {
    __syncthreads();
    gload_lds16(ga0 + k0,       la0);
    gload_lds16(ga0 + k16 + k0, la1);
    gload_lds16(gb0 + k0,       lb0);
    gload_lds16(gb0 + k16 + k0, lb1);
    __syncthreads();

    bf16x8 af[4], bfr[4];
#pragma unroll
    for (int i = 0; i < 4; ++i) af[i]  = *(const bf16x8*)&As[(wr * 64 + i * 16 + lr) * 32 + lg * 8];
#pragma unroll
    for (int j = 0; j < 4; ++j) bfr[j] = *(const bf16x8*)&Bs[(wc * 64 + j * 16 + lr) * 32 + lg * 8];
#pragma unroll
    for (int i = 0; i < 4; ++i)
#pragma unroll
      for (int j = 0; j < 4; ++j)
        acc[i][j] = __builtin_amdgcn_mfma_f32_16x16x32_bf16(af[i], bfr[j], acc[i][j], 0, 0, 0);
  }
#pragma unroll
  for (int i = 0; i < 4; ++i)
#pragma unroll
    for (int j = 0; j < 4; ++j) {
      const int row0 = (int)m0 + wr * 64 + i * 16 + lg * 4;
      const int col  = (int)n0 + wc * 64 + j * 16 + lr;
#pragma unroll
      for (int r = 0; r < 4; ++r) {
        const int row = row0 + r;
        if (MODE == 0) {
          ((float*)outv)[(size_t)row * N + col] = acc[i][j][r];
        } else {
          bf16_t* out = (bf16_t*)outv;
          const bf16_t val = (bf16_t)acc[i][j][r];
          const int b = row >> 11, s = row & (S_ - 1);
          const int h = col >> 8,  hd = col & (HD_ - 1);
          if (MODE == 1) out[((size_t)(b * nh + h) * S_ + s) * HD_ + hd] = val;
          else           out[((size_t)(b * NKV_ + h) * HD_ + hd) * S_ + s] = val;
        }
      }
    }
}

// ---------------- fused RMSNorm + RoPE (in place), (b, s, h) block order ----------------
template<int LOGNH>
__global__ __launch_bounds__(256) void normrope_kernel(bf16_t* __restrict__ x,
                                                       const float* __restrict__ w,
                                                       const float* __restrict__ cosb,
                                                       const float* __restrict__ sinb,
                                                       float* __restrict__ rownorm) {
  const int gid  = blockIdx.x * 4 + (threadIdx.x >> 6);  // (b, s, h) order: h innermost
  const int lane = threadIdx.x & 63;
  const int nh = 1 << LOGNH;
  const int h  = gid & (nh - 1);
  const int bs = gid >> LOGNH;                 // b*S + s
  const int b  = bs >> 11, s = bs & (S_ - 1);
  const int rowi = (b * nh + h) * S_ + s;

  bf16_t* ptr = x + (size_t)rowi * HD_ + lane * 4;
  bf16x4 xv = *(const bf16x4*)ptr;
  float v0 = (float)xv[0], v1 = (float)xv[1], v2 = (float)xv[2], v3 = (float)xv[3];
  float ss = v0 * v0 + v1 * v1 + v2 * v2 + v3 * v3;
#pragma unroll
  for (int off = 1; off < 64; off <<= 1) ss += __shfl_xor(ss, off);
  float r = rsqrtf(ss * (1.0f / HD_) + 1e-6f);

  float4 wv = *(const float4*)(w + lane * 4);
  float x0 = v0 * r * (1.0f + wv.x);
  float x1 = v1 * r * (1.0f + wv.y);
  float x2 = v2 * r * (1.0f + wv.z);
  float x3 = v3 * r * (1.0f + wv.w);

  if (rownorm != nullptr) {   // row norm^2 after scale (RoPE preserves norm)
    float s2 = x0 * x0 + x1 * x1 + x2 * x2 + x3 * x3;
#pragma unroll
    for (int off = 1; off < 64; off <<= 1) s2 += __shfl_xor(s2, off);
    if (lane == 0) rownorm[rowi] = s2;
  }

  float p0 = __shfl_xor(x0, 32);
  float p1 = __shfl_xor(x1, 32);
  float p2 = __shfl_xor(x2, 32);
  float p3 = __shfl_xor(x3, 32);
  float sgn = (lane < 32) ? -1.0f : 1.0f;

  float4 c  = *(const float4*)(cosb + (size_t)bs * HD_ + lane * 4);
  float4 sn = *(const float4*)(sinb + (size_t)bs * HD_ + lane * 4);
  bf16x4 o;
  o[0] = (bf16_t)(x0 * c.x + sgn * p0 * sn.x);
  o[1] = (bf16_t)(x1 * c.y + sgn * p1 * sn.y);
  o[2] = (bf16_t)(x2 * c.z + sgn * p2 * sn.z);
  o[3] = (bf16_t)(x3 * c.w + sgn * p3 * sn.w);
  *(bf16x4*)ptr = o;
}

// ---------------- per-(b,kv-head) max of knorm ----------------
__global__ __launch_bounds__(256) void kmax_reduce_kernel(const float* __restrict__ knorm,
                                                          float* __restrict__ km) {
  __shared__ float red[4];
  const int t = threadIdx.x;
  const float* src = knorm + (size_t)blockIdx.x * S_;
  float m = 0.0f;
  for (int i = t; i < S_; i += 256) m = fmaxf(m, src[i]);
#pragma unroll
  for (int off = 1; off < 64; off <<= 1) m = fmaxf(m, __shfl_xor(m, off));
  if ((t & 63) == 0) red[t >> 6] = m;
  __syncthreads();
  if (t == 0) km[blockIdx.x] = fmaxf(fmaxf(red[0], red[1]), fmaxf(red[2], red[3]));
}

// ---------------- single-pass flash attention (round-8 structure) ----------------
// 1-D XCD-pinned grid: all 64 blocks of a (b,kvh) group on one XCD; LPT within group.
// No launch_bounds min-wave clamp (VGPR ~104 needed; clamping to 64 caused spills, R10).
__global__ __launch_bounds__(256) void attn1p_kernel(const bf16_t* __restrict__ qb,
                                                     const bf16_t* __restrict__ kb,
                                                     const bf16_t* __restrict__ vt,
                                                     const float* __restrict__ kmaxbuf,
                                                     float* __restrict__ wout,
                                                     float* __restrict__ linv,
                                                     bf16_t* __restrict__ ctx) {
  __shared__ __align__(16) bf16_t Ks[32][264];      // +8 pad
  __shared__ __align__(16) bf16_t Vs[256][40];      // d-major, +8 pad
  __shared__ __align__(16) bf16_t p_lds[4][16][40];
  __shared__ float qn_lds[4][16];

  const int t = threadIdx.x, w = t >> 6, lane = t & 63;
  const int lr = lane & 15, lg = lane >> 4, rloc = lg * 4;

  // XCD-pinned decode (wgid%8 = XCD round-robin); LPT: heavy q-buckets first
  const int wgid = blockIdx.x;
  const int g    = ((wgid >> 9) << 3) | (wgid & 7);   // (b*NKV + kvh) group, 0..15
  const int idx  = (wgid >> 3) & 63;
  const int b    = g >> 3, kvh = g & 7;
  const int h    = kvh * 2 + (idx >> 5);
  const int qbucket = 31 - (idx & 31);                // descending: longest first
  const int bh   = b * NH_ + h;
  const int q0b  = qbucket * 64;
  const int q0   = q0b + w * 16;

  const bf16_t* qptr = qb + ((size_t)bh * S_ + q0 + lr) * HD_ + lg * 8;
  bf16x8 qf[8];
#pragma unroll
  for (int c = 0; c < 8; ++c) qf[c] = *(const bf16x8*)(qptr + c * 32);

  float qn = 0.0f;
#pragma unroll
  for (int c = 0; c < 8; ++c)
#pragma unroll
    for (int e = 0; e < 8; ++e) { float v = (float)qf[c][e]; qn += v * v; }
  qn += __shfl_xor(qn, 16);
  qn += __shfl_xor(qn, 32);
  if (lg == 0) qn_lds[w][lr] = qn;
  __syncthreads();
  const float kmax2 = kmaxbuf[b * NKV_ + kvh];
  float mb[4];
#pragma unroll
  for (int r = 0; r < 4; ++r)
    mb[r] = SCALE_ * sqrtf(qn_lds[w][rloc + r] * kmax2) + 1.0f;  // >= any score, with margin

  float l[4] = {0.f, 0.f, 0.f, 0.f};
  f32x4 oacc[16] = {};
  const int nkt = (q0b + 64) >> 5;
  float* wrow = wout + ((size_t)bh * S_ + q0) * S_;
  const bf16_t* kgb = kb + (size_t)(b * NKV_ + kvh) * S_ * HD_;
  const bf16_t* vgb = vt + (size_t)(b * NKV_ + kvh) * HD_ * S_;

  const int s_st = t >> 3, c_st = (t & 7) * 32;   // K staging: row s_st, 4x8 cols
  const int vd   = t >> 3, vc   = (t & 7) * 4;    // V staging: rows vd+32i, 4 cols

  for (int kt = 0; kt < nkt; ++kt) {
    const int colb = kt * 32;
    __syncthreads();   // previous tile's LDS reads complete
    {  // stage K tile (32 x 256) coalesced
      const bf16_t* src = kgb + (size_t)(colb + s_st) * HD_ + c_st;
      bf16x8 k0 = *(const bf16x8*)(src);
      bf16x8 k1 = *(const bf16x8*)(src + 8);
      bf16x8 k2 = *(const bf16x8*)(src + 16);
      bf16x8 k3 = *(const bf16x8*)(src + 24);
      *(bf16x8*)&Ks[s_st][c_st]      = k0;
      *(bf16x8*)&Ks[s_st][c_st + 8]  = k1;
      *(bf16x8*)&Ks[s_st][c_st + 16] = k2;
      *(bf16x8*)&Ks[s_st][c_st + 24] = k3;
    }
#pragma unroll
    for (int i = 0; i < 8; ++i) {  // stage V tile (256 d x 32 s) from vt
      const int d = vd + i * 32;
      bf16x4 vv = *(const bf16x4*)(vgb + (size_t)d * S_ + colb + vc);
      *(bf16x4*)&Vs[d][vc] = vv;
    }
    __syncthreads();

    if (colb <= q0 + 15) {   // wave active for this tile
      f32x4 s0 = {0.f, 0.f, 0.f, 0.f}, s1 = {0.f, 0.f, 0.f, 0.f};
#pragma unroll
      for (int c = 0; c < 8; ++c) {
        bf16x8 k0 = *(const bf16x8*)&Ks[lr][c * 32 + lg * 8];
        bf16x8 k1 = *(const bf16x8*)&Ks[16 + lr][c * 32 + lg * 8];
        s0 = __builtin_amdgcn_mfma_f32_16x16x32_bf16(qf[c], k0, s0, 0, 0, 0);
        s1 = __builtin_amdgcn_mfma_f32_16x16x32_bf16(qf[c], k1, s1, 0, 0, 0);
      }
      const int col0 = colb + lr, col1 = col0 + 16;
#pragma unroll
      for (int r = 0; r < 4; ++r) {
        const int row = q0 + rloc + r;
        const float pa = (col0 <= row) ? __expf(s0[r] * SCALE_ - mb[r]) : 0.0f;
        const float pb = (col1 <= row) ? __expf(s1[r] * SCALE_ - mb[r]) : 0.0f;
        l[r] += pa + pb;
        wrow[(size_t)(rloc + r) * S_ + col0] = pa;
        wrow[(size_t)(rloc + r) * S_ + col1] = pb;
        p_lds[w][rloc + r][lr]      = (bf16_t)pa;
        p_lds[w][rloc + r][lr + 16] = (bf16_t)pb;
      }
      bf16x8 pf = *(const bf16x8*)&p_lds[w][lr][lg * 8];   // P as A-fragment
#pragma unroll
      for (int df = 0; df < 16; ++df) {
        bf16x8 vf = *(const bf16x8*)&Vs[df * 16 + lr][lg * 8];
        oacc[df] = __builtin_amdgcn_mfma_f32_16x16x32_bf16(pf, vf, oacc[df], 0, 0, 0);
      }
    }
  }
  // row sum l across lr lanes
#pragma unroll
  for (int r = 0; r < 4; ++r) {
    l[r] += __shfl_xor(l[r], 1);
    l[r] += __shfl_xor(l[r], 2);
    l[r] += __shfl_xor(l[r], 4);
    l[r] += __shfl_xor(l[r], 8);
  }
  float invl[4];
#pragma unroll
  for (int r = 0; r < 4; ++r) invl[r] = 1.0f / l[r];

  bf16_t* cp = ctx + ((size_t)b * S_ + q0) * DQ_ + h * HD_;
#pragma unroll
  for (int df = 0; df < 16; ++df)
#pragma unroll
    for (int r = 0; r < 4; ++r)
      cp[(size_t)(rloc + r) * DQ_ + df * 16 + lr] = (bf16_t)(oacc[df][r] * invl[r]);

  if (lr == 0) {
#pragma unroll
    for (int r = 0; r < 4; ++r) linv[(size_t)bh * S_ + q0 + rloc + r] = invl[r];
  }
}

// ---------------- weights post-pass: scale lower triangle by 1/l, zero upper ----------------
__global__ __launch_bounds__(256) void wscale_kernel(float* __restrict__ wbuf,
                                                     const float* __restrict__ linv) {
  const int wv = threadIdx.x >> 6, lane = threadIdx.x & 63;
  const size_t rg = (size_t)blockIdx.x * 4 + wv;     // global row in (B*NH, S)
  const int row = (int)(rg & (S_ - 1));
  const float inv = linv[rg];
  float* base = wbuf + rg * S_;
#pragma unroll
  for (int i = 0; i < 8; ++i) {
    const int c0 = (i * 64 + lane) * 4;
    float4 v;
    if (c0 > row) {
      v = make_float4(0.f, 0.f, 0.f, 0.f);
    } else {
      v = *(const float4*)(base + c0);
      v.x = (c0 + 0 <= row) ? v.x * inv : 0.f;
      v.y = (c0 + 1 <= row) ? v.y * inv : 0.f;
      v.z = (c0 + 2 <= row) ? v.z * inv : 0.f;
      v.w = (c0 + 3 <= row) ? v.w * inv : 0.f;
    }
    *(float4*)(base + c0) = v;
  }
}

// ---------------- launch ----------------
extern "C" void kernel_launch(void* const* d_in, const int* in_sizes, int n_in,
                              void* d_out, int out_size, void* d_ws, size_t ws_size,
                              hipStream_t stream) {
  const float* hs   = (const float*)d_in[0];
  const float* cosb = (const float*)d_in[1];
  const float* sinb = (const float*)d_in[2];
  // d_in[3] attention_mask: recomputed causally in-kernel
  const float* Wq = (const float*)d_in[4];
  const float* Wk = (const float*)d_in[5];
  const float* Wv = (const float*)d_in[6];
  const float* Wo = (const float*)d_in[7];
  const float* qw = (const float*)d_in[8];
  const float* kw = (const float*)d_in[9];

  char* ws = (char*)d_ws;
  bf16_t* qb    = (bf16_t*)(ws + 0);            // 33,554,432  (B,NH,S,HD)
  bf16_t* kb    = (bf16_t*)(ws + 33554432);     // 16,777,216  (B,NKV,S,HD)
  bf16_t* vt    = (bf16_t*)(ws + 50331648);     // 16,777,216  (B,NKV,HD,S)
  bf16_t* ctx   = (bf16_t*)(ws + 67108864);     // 33,554,432  (B,S,NH*HD)
  float*  linv  = (float*)(ws + 100663296);     //    262,144
  float*  knorm = (float*)(ws + 100925440);     //    131,072
  float*  km    = (float*)(ws + 101056512);     //        128
  bf16_t* hsb   = (bf16_t*)(ws + 101056640);    // 29,360,128
  bf16_t* wqb   = (bf16_t*)(ws + 130416768);    // 29,360,128
  bf16_t* wkb   = (bf16_t*)(ws + 159776896);    // 14,680,064
  bf16_t* wvb   = (bf16_t*)(ws + 174456960);    // 14,680,064
  bf16_t* wob   = (bf16_t*)(ws + 189137024);    // 29,360,128  -> total 218,497,152

  float* out      = (float*)d_out;
  float* attn_out = out;                            // (B,S,HID) f32
  float* weights  = out + (size_t)B_ * S_ * HID_;   // (B,NH,S,S) f32

  const int M = B_ * S_;  // 4096

  // 0) one-shot bf16 conversion of activations + weights
  cvt_kernel<<<14336, 256, 0, stream>>>(hs, hsb, (B_ * S_ * HID_) / 4);
  cvt_kernel<<<14336, 256, 0, stream>>>(Wq, wqb, (DQ_ * HID_) / 4);
  cvt_kernel<<<7168,  256, 0, stream>>>(Wk, wkb, (DKV_ * HID_) / 4);
  cvt_kernel<<<7168,  256, 0, stream>>>(Wv, wvb, (DKV_ * HID_) / 4);
  cvt_kernel<<<14336, 256, 0, stream>>>(Wo, wob, (HID_ * DQ_) / 4);

  // 1) projections (bf16 x bf16, global_load_lds staging)
  gemm_lds<1><<<dim3(DQ_ / 128, M / 128), 256, 0, stream>>>(hsb, wqb, qb, M, DQ_, HID_, NH_);
  gemm_lds<1><<<dim3(DKV_ / 128, M / 128), 256, 0, stream>>>(hsb, wkb, kb, M, DKV_, HID_, NKV_);
  gemm_lds<2><<<dim3(DKV_ / 128, M / 128), 256, 0, stream>>>(hsb, wvb, vt, M, DKV_, HID_, NKV_);

  // 2) norm + rope (in place); K pass also stores per-row |k|^2
  normrope_kernel<4><<<(B_ * S_ * NH_) / 4, 256, 0, stream>>>(qb, qw, cosb, sinb, nullptr);
  normrope_kernel<3><<<(B_ * S_ * NKV_) / 4, 256, 0, stream>>>(kb, kw, cosb, sinb, knorm);
  kmax_reduce_kernel<<<B_ * NKV_, 256, 0, stream>>>(knorm, km);

  // 3) single-pass attention (p-tilde into weights buffer), XCD-pinned 1-D grid
  attn1p_kernel<<<(S_ / 64) * (B_ * NH_), 256, 0, stream>>>(qb, kb, vt, km, weights, linv, ctx);

  // 4) weights normalization + upper-triangle zeros
  wscale_kernel<<<(B_ * NH_ * S_) / 4, 256, 0, stream>>>(weights, linv);

  // 5) output projection -> d_out (f32)
  gemm_lds<0><<<dim3(HID_ / 128, M / 128), 256, 0, stream>>>(ctx, wob, attn_out, M, HID_, DQ_, 0);
}

// Round 14
// 990.088 us; speedup vs baseline: 2.3194x; 1.0591x over previous
//
#include <hip/hip_runtime.h>

// ---------------- problem constants ----------------
#define B_    2
#define S_    2048
#define HID_  3584
#define NH_   16
#define NKV_  8
#define HD_   256
#define DQ_   (NH_ * HD_)    // 4096
#define DKV_  (NKV_ * HD_)   // 2048

static constexpr float SCALE_ = 0.0625f;   // 256^-0.5

typedef __bf16 bf16_t;
typedef __bf16 bf16x8 __attribute__((ext_vector_type(8)));
typedef __bf16 bf16x4 __attribute__((ext_vector_type(4)));
typedef float  f32x4  __attribute__((ext_vector_type(4)));

// ---------------- f32 -> bf16 convert ----------------
__global__ __launch_bounds__(256) void cvt_kernel(const float* __restrict__ in,
                                                  bf16_t* __restrict__ out, int n4) {
  int i = blockIdx.x * 256 + threadIdx.x;
  if (i < n4) {
    float4 v = ((const float4*)in)[i];
    bf16x4 o;
    o[0] = (bf16_t)v.x; o[1] = (bf16_t)v.y; o[2] = (bf16_t)v.z; o[3] = (bf16_t)v.w;
    ((bf16x4*)out)[i] = o;
  }
}

// ---------------- async global->LDS, 16B per lane ----------------
__device__ inline void gload_lds16(const bf16_t* g, bf16_t* l) {
  __builtin_amdgcn_global_load_lds(
      (const __attribute__((address_space(1))) void*)g,
      (__attribute__((address_space(3))) void*)l, 16, 0, 0);
}

// ---------------- GEMM (m97 structure, BK=64 + XOR swizzle): C[m][n] = sum_k A[m][k]*Bt[n][k] ----------------
// BK=64 halves barrier count vs BK=32. Row stride 128B would be a 16-way bank conflict on
// ds_read_b128, so the global SOURCE is pre-swizzled (col16 ^= row&7) and the LDS read applies
// the same XOR (involution; global_load_lds dest must stay linear).
// MODE 0: OUT f32, plain row-major [M][N]          (o-proj -> d_out)
// MODE 1: OUT bf16, relayout to (B, nh, S, HD)     (Q, K projections)
// MODE 2: OUT bf16, transpose to (B, NKV, HD, S)   (V projection)
template<int MODE>
__global__ __launch_bounds__(256) void gemm_lds(const bf16_t* __restrict__ A,
                                                const bf16_t* __restrict__ Bt,
                                                void* __restrict__ outv,
                                                int M, int N, int K, int nh) {
  __shared__ __align__(16) bf16_t As[128 * 64];   // 16 KB
  __shared__ __align__(16) bf16_t Bs[128 * 64];   // 16 KB
  const int t = threadIdx.x;
  const int lane = t & 63, wv = t >> 6;
  const int wr = wv >> 1, wc = wv & 1;
  const int lr = lane & 15, lg = lane >> 4;
  const size_t m0 = (size_t)blockIdx.y * 128, n0 = (size_t)blockIdx.x * 128;

  // staging: 8 rows per gload (8 lanes/row, 16B each); source col pre-swizzled
  const int srow = wv * 32 + (lane >> 3);
  const int scsw = ((lane & 7) ^ ((lane >> 3) & 7)) * 8;
  const bf16_t* ga0 = A  + (m0 + srow) * (size_t)K + scsw;
  const bf16_t* gb0 = Bt + (n0 + srow) * (size_t)K + scsw;

  f32x4 acc[4][4] = {};
  for (int k0 = 0; k0 < K; k0 += 64) {
    __syncthreads();
#pragma unroll
    for (int i = 0; i < 4; ++i) {
      gload_lds16(ga0 + (size_t)(i * 8) * K + k0, &As[(wv * 32 + i * 8) * 64]);
      gload_lds16(gb0 + (size_t)(i * 8) * K + k0, &Bs[(wv * 32 + i * 8) * 64]);
    }
    __syncthreads();

#pragma unroll
    for (int kk = 0; kk < 64; kk += 32) {
      const int c16 = (kk >> 3) + lg;                 // col16 index of fragment
      const int swz = (c16 ^ (lr & 7)) * 8;           // XOR-swizzled LDS col
      bf16x8 af[4], bfr[4];
#pragma unroll
      for (int i = 0; i < 4; ++i) af[i]  = *(const bf16x8*)&As[(wr * 64 + i * 16 + lr) * 64 + swz];
#pragma unroll
      for (int j = 0; j < 4; ++j) bfr[j] = *(const bf16x8*)&Bs[(wc * 64 + j * 16 + lr) * 64 + swz];
#pragma unroll
      for (int i = 0; i < 4; ++i)
#pragma unroll
        for (int j = 0; j < 4; ++j)
          acc[i][j] = __builtin_amdgcn_mfma_f32_16x16x32_bf16(af[i], bfr[j], acc[i][j], 0, 0, 0);
    }
  }
#pragma unroll
  for (int i = 0; i < 4; ++i)
#pragma unroll
    for (int j = 0; j < 4; ++j) {
      const int row0 = (int)m0 + wr * 64 + i * 16 + lg * 4;
      const int col  = (int)n0 + wc * 64 + j * 16 + lr;
#pragma unroll
      for (int r = 0; r < 4; ++r) {
        const int row = row0 + r;
        if (MODE == 0) {
          ((float*)outv)[(size_t)row * N + col] = acc[i][j][r];
        } else {
          bf16_t* out = (bf16_t*)outv;
          const bf16_t val = (bf16_t)acc[i][j][r];
          const int b = row >> 11, s = row & (S_ - 1);
          const int h = col >> 8,  hd = col & (HD_ - 1);
          if (MODE == 1) out[((size_t)(b * nh + h) * S_ + s) * HD_ + hd] = val;
          else           out[((size_t)(b * NKV_ + h) * HD_ + hd) * S_ + s] = val;
        }
      }
    }
}

// ---------------- fused RMSNorm + RoPE (in place), (b, s, h) block order ----------------
template<int LOGNH>
__global__ __launch_bounds__(256) void normrope_kernel(bf16_t* __restrict__ x,
                                                       const float* __restrict__ w,
                                                       const float* __restrict__ cosb,
                                                       const float* __restrict__ sinb,
                                                       float* __restrict__ rownorm) {
  const int gid  = blockIdx.x * 4 + (threadIdx.x >> 6);  // (b, s, h) order: h innermost
  const int lane = threadIdx.x & 63;
  const int nh = 1 << LOGNH;
  const int h  = gid & (nh - 1);
  const int bs = gid >> LOGNH;                 // b*S + s
  const int b  = bs >> 11, s = bs & (S_ - 1);
  const int rowi = (b * nh + h) * S_ + s;

  bf16_t* ptr = x + (size_t)rowi * HD_ + lane * 4;
  bf16x4 xv = *(const bf16x4*)ptr;
  float v0 = (float)xv[0], v1 = (float)xv[1], v2 = (float)xv[2], v3 = (float)xv[3];
  float ss = v0 * v0 + v1 * v1 + v2 * v2 + v3 * v3;
#pragma unroll
  for (int off = 1; off < 64; off <<= 1) ss += __shfl_xor(ss, off);
  float r = rsqrtf(ss * (1.0f / HD_) + 1e-6f);

  float4 wv = *(const float4*)(w + lane * 4);
  float x0 = v0 * r * (1.0f + wv.x);
  float x1 = v1 * r * (1.0f + wv.y);
  float x2 = v2 * r * (1.0f + wv.z);
  float x3 = v3 * r * (1.0f + wv.w);

  if (rownorm != nullptr) {   // row norm^2 after scale (RoPE preserves norm)
    float s2 = x0 * x0 + x1 * x1 + x2 * x2 + x3 * x3;
#pragma unroll
    for (int off = 1; off < 64; off <<= 1) s2 += __shfl_xor(s2, off);
    if (lane == 0) rownorm[rowi] = s2;
  }

  float p0 = __shfl_xor(x0, 32);
  float p1 = __shfl_xor(x1, 32);
  float p2 = __shfl_xor(x2, 32);
  float p3 = __shfl_xor(x3, 32);
  float sgn = (lane < 32) ? -1.0f : 1.0f;

  float4 c  = *(const float4*)(cosb + (size_t)bs * HD_ + lane * 4);
  float4 sn = *(const float4*)(sinb + (size_t)bs * HD_ + lane * 4);
  bf16x4 o;
  o[0] = (bf16_t)(x0 * c.x + sgn * p0 * sn.x);
  o[1] = (bf16_t)(x1 * c.y + sgn * p1 * sn.y);
  o[2] = (bf16_t)(x2 * c.z + sgn * p2 * sn.z);
  o[3] = (bf16_t)(x3 * c.w + sgn * p3 * sn.w);
  *(bf16x4*)ptr = o;
}

// ---------------- per-(b,kv-head) max of knorm ----------------
__global__ __launch_bounds__(256) void kmax_reduce_kernel(const float* __restrict__ knorm,
                                                          float* __restrict__ km) {
  __shared__ float red[4];
  const int t = threadIdx.x;
  const float* src = knorm + (size_t)blockIdx.x * S_;
  float m = 0.0f;
  for (int i = t; i < S_; i += 256) m = fmaxf(m, src[i]);
#pragma unroll
  for (int off = 1; off < 64; off <<= 1) m = fmaxf(m, __shfl_xor(m, off));
  if ((t & 63) == 0) red[t >> 6] = m;
  __syncthreads();
  if (t == 0) km[blockIdx.x] = fmaxf(fmaxf(red[0], red[1]), fmaxf(red[2], red[3]));
}

// ---------------- single-pass flash attention (round-8 structure, XCD-pinned, LPT) ----------------
// p-tilde stores now routed through p_lds: 2 x f32x4 coalesced stores per lane per tile
// (was 8 narrow stores). Weights carry bf16-rounded p-tilde (same rounding as PV path).
__global__ __launch_bounds__(256) void attn1p_kernel(const bf16_t* __restrict__ qb,
                                                     const bf16_t* __restrict__ kb,
                                                     const bf16_t* __restrict__ vt,
                                                     const float* __restrict__ kmaxbuf,
                                                     float* __restrict__ wout,
                                                     float* __restrict__ linv,
                                                     bf16_t* __restrict__ ctx) {
  __shared__ __align__(16) bf16_t Ks[32][264];      // +8 pad
  __shared__ __align__(16) bf16_t Vs[256][40];      // d-major, +8 pad
  __shared__ __align__(16) bf16_t p_lds[4][16][40];
  __shared__ float qn_lds[4][16];

  const int t = threadIdx.x, w = t >> 6, lane = t & 63;
  const int lr = lane & 15, lg = lane >> 4, rloc = lg * 4;

  // XCD-pinned decode (wgid%8 = XCD round-robin); LPT: heavy q-buckets first
  const int wgid = blockIdx.x;
  const int g    = ((wgid >> 9) << 3) | (wgid & 7);   // (b*NKV + kvh) group, 0..15
  const int idx  = (wgid >> 3) & 63;
  const int b    = g >> 3, kvh = g & 7;
  const int h    = kvh * 2 + (idx >> 5);
  const int qbucket = 31 - (idx & 31);                // descending: longest first
  const int bh   = b * NH_ + h;
  const int q0b  = qbucket * 64;
  const int q0   = q0b + w * 16;

  const bf16_t* qptr = qb + ((size_t)bh * S_ + q0 + lr) * HD_ + lg * 8;
  bf16x8 qf[8];
#pragma unroll
  for (int c = 0; c < 8; ++c) qf[c] = *(const bf16x8*)(qptr + c * 32);

  float qn = 0.0f;
#pragma unroll
  for (int c = 0; c < 8; ++c)
#pragma unroll
    for (int e = 0; e < 8; ++e) { float v = (float)qf[c][e]; qn += v * v; }
  qn += __shfl_xor(qn, 16);
  qn += __shfl_xor(qn, 32);
  if (lg == 0) qn_lds[w][lr] = qn;
  __syncthreads();
  const float kmax2 = kmaxbuf[b * NKV_ + kvh];
  float mb[4];
#pragma unroll
  for (int r = 0; r < 4; ++r)
    mb[r] = SCALE_ * sqrtf(qn_lds[w][rloc + r] * kmax2) + 1.0f;  // >= any score, with margin

  float l[4] = {0.f, 0.f, 0.f, 0.f};
  f32x4 oacc[16] = {};
  const int nkt = (q0b + 64) >> 5;
  float* wrow = wout + ((size_t)bh * S_ + q0) * S_;
  const bf16_t* kgb = kb + (size_t)(b * NKV_ + kvh) * S_ * HD_;
  const bf16_t* vgb = vt + (size_t)(b * NKV_ + kvh) * HD_ * S_;

  const int s_st = t >> 3, c_st = (t & 7) * 32;   // K staging: row s_st, 4x8 cols
  const int vd   = t >> 3, vc   = (t & 7) * 4;    // V staging: rows vd+32i, 4 cols
  const int prow = lane >> 2, pcol = (lane & 3) * 8;  // p-tilde store geometry

  for (int kt = 0; kt < nkt; ++kt) {
    const int colb = kt * 32;
    __syncthreads();   // previous tile's LDS reads complete
    {  // stage K tile (32 x 256) coalesced
      const bf16_t* src = kgb + (size_t)(colb + s_st) * HD_ + c_st;
      bf16x8 k0 = *(const bf16x8*)(src);
      bf16x8 k1 = *(const bf16x8*)(src + 8);
      bf16x8 k2 = *(const bf16x8*)(src + 16);
      bf16x8 k3 = *(const bf16x8*)(src + 24);
      *(bf16x8*)&Ks[s_st][c_st]      = k0;
      *(bf16x8*)&Ks[s_st][c_st + 8]  = k1;
      *(bf16x8*)&Ks[s_st][c_st + 16] = k2;
      *(bf16x8*)&Ks[s_st][c_st + 24] = k3;
    }
#pragma unroll
    for (int i = 0; i < 8; ++i) {  // stage V tile (256 d x 32 s) from vt
      const int d = vd + i * 32;
      bf16x4 vv = *(const bf16x4*)(vgb + (size_t)d * S_ + colb + vc);
      *(bf16x4*)&Vs[d][vc] = vv;
    }
    __syncthreads();

    if (colb <= q0 + 15) {   // wave active for this tile
      f32x4 s0 = {0.f, 0.f, 0.f, 0.f}, s1 = {0.f, 0.f, 0.f, 0.f};
#pragma unroll
      for (int c = 0; c < 8; ++c) {
        bf16x8 k0 = *(const bf16x8*)&Ks[lr][c * 32 + lg * 8];
        bf16x8 k1 = *(const bf16x8*)&Ks[16 + lr][c * 32 + lg * 8];
        s0 = __builtin_amdgcn_mfma_f32_16x16x32_bf16(qf[c], k0, s0, 0, 0, 0);
        s1 = __builtin_amdgcn_mfma_f32_16x16x32_bf16(qf[c], k1, s1, 0, 0, 0);
      }
      const int col0 = colb + lr, col1 = col0 + 16;
#pragma unroll
      for (int r = 0; r < 4; ++r) {
        const int row = q0 + rloc + r;
        const float pa = (col0 <= row) ? __expf(s0[r] * SCALE_ - mb[r]) : 0.0f;
        const float pb = (col1 <= row) ? __expf(s1[r] * SCALE_ - mb[r]) : 0.0f;
        l[r] += pa + pb;
        p_lds[w][rloc + r][lr]      = (bf16_t)pa;
        p_lds[w][rloc + r][lr + 16] = (bf16_t)pb;
      }
      bf16x8 pf = *(const bf16x8*)&p_lds[w][lr][lg * 8];   // P as A-fragment
#pragma unroll
      for (int df = 0; df < 16; ++df) {
        bf16x8 vf = *(const bf16x8*)&Vs[df * 16 + lr][lg * 8];
        oacc[df] = __builtin_amdgcn_mfma_f32_16x16x32_bf16(pf, vf, oacc[df], 0, 0, 0);
      }
      // coalesced p-tilde store: lane covers row=lane>>2, 8 cols from (lane&3)*8
      {
        bf16x8 pv = *(const bf16x8*)&p_lds[w][prow][pcol];
        float* dst = wrow + (size_t)prow * S_ + colb + pcol;
        f32x4 lo = {(float)pv[0], (float)pv[1], (float)pv[2], (float)pv[3]};
        f32x4 hi = {(float)pv[4], (float)pv[5], (float)pv[6], (float)pv[7]};
        *(f32x4*)dst = lo;
        *(f32x4*)(dst + 4) = hi;
      }
    }
  }
  // row sum l across lr lanes
#pragma unroll
  for (int r = 0; r < 4; ++r) {
    l[r] += __shfl_xor(l[r], 1);
    l[r] += __shfl_xor(l[r], 2);
    l[r] += __shfl_xor(l[r], 4);
    l[r] += __shfl_xor(l[r], 8);
  }
  float invl[4];
#pragma unroll
  for (int r = 0; r < 4; ++r) invl[r] = 1.0f / l[r];

  bf16_t* cp = ctx + ((size_t)b * S_ + q0) * DQ_ + h * HD_;
#pragma unroll
  for (int df = 0; df < 16; ++df)
#pragma unroll
    for (int r = 0; r < 4; ++r)
      cp[(size_t)(rloc + r) * DQ_ + df * 16 + lr] = (bf16_t)(oacc[df][r] * invl[r]);

  if (lr == 0) {
#pragma unroll
    for (int r = 0; r < 4; ++r) linv[(size_t)bh * S_ + q0 + rloc + r] = invl[r];
  }
}

// ---------------- weights post-pass: scale lower triangle by 1/l, zero upper ----------------
__global__ __launch_bounds__(256) void wscale_kernel(float* __restrict__ wbuf,
                                                     const float* __restrict__ linv) {
  const int wv = threadIdx.x >> 6, lane = threadIdx.x & 63;
  const size_t rg = (size_t)blockIdx.x * 4 + wv;     // global row in (B*NH, S)
  const int row = (int)(rg & (S_ - 1));
  const float inv = linv[rg];
  float* base = wbuf + rg * S_;
#pragma unroll
  for (int i = 0; i < 8; ++i) {
    const int c0 = (i * 64 + lane) * 4;
    float4 v;
    if (c0 > row) {
      v = make_float4(0.f, 0.f, 0.f, 0.f);
    } else {
      v = *(const float4*)(base + c0);
      v.x = (c0 + 0 <= row) ? v.x * inv : 0.f;
      v.y = (c0 + 1 <= row) ? v.y * inv : 0.f;
      v.z = (c0 + 2 <= row) ? v.z * inv : 0.f;
      v.w = (c0 + 3 <= row) ? v.w * inv : 0.f;
    }
    *(float4*)(base + c0) = v;
  }
}

// ---------------- launch ----------------
extern "C" void kernel_launch(void* const* d_in, const int* in_sizes, int n_in,
                              void* d_out, int out_size, void* d_ws, size_t ws_size,
                              hipStream_t stream) {
  const float* hs   = (const float*)d_in[0];
  const float* cosb = (const float*)d_in[1];
  const float* sinb = (const float*)d_in[2];
  // d_in[3] attention_mask: recomputed causally in-kernel
  const float* Wq = (const float*)d_in[4];
  const float* Wk = (const float*)d_in[5];
  const float* Wv = (const float*)d_in[6];
  const float* Wo = (const float*)d_in[7];
  const float* qw = (const float*)d_in[8];
  const float* kw = (const float*)d_in[9];

  char* ws = (char*)d_ws;
  bf16_t* qb    = (bf16_t*)(ws + 0);            // 33,554,432  (B,NH,S,HD)
  bf16_t* kb    = (bf16_t*)(ws + 33554432);     // 16,777,216  (B,NKV,S,HD)
  bf16_t* vt    = (bf16_t*)(ws + 50331648);     // 16,777,216  (B,NKV,HD,S)
  bf16_t* ctx   = (bf16_t*)(ws + 67108864);     // 33,554,432  (B,S,NH*HD)
  float*  linv  = (float*)(ws + 100663296);     //    262,144
  float*  knorm = (float*)(ws + 100925440);     //    131,072
  float*  km    = (float*)(ws + 101056512);     //        128
  bf16_t* hsb   = (bf16_t*)(ws + 101056640);    // 29,360,128
  bf16_t* wqb   = (bf16_t*)(ws + 130416768);    // 29,360,128
  bf16_t* wkb   = (bf16_t*)(ws + 159776896);    // 14,680,064
  bf16_t* wvb   = (bf16_t*)(ws + 174456960);    // 14,680,064
  bf16_t* wob   = (bf16_t*)(ws + 189137024);    // 29,360,128  -> total 218,497,152

  float* out      = (float*)d_out;
  float* attn_out = out;                            // (B,S,HID) f32
  float* weights  = out + (size_t)B_ * S_ * HID_;   // (B,NH,S,S) f32

  const int M = B_ * S_;  // 4096

  // 0) one-shot bf16 conversion of activations + weights
  cvt_kernel<<<14336, 256, 0, stream>>>(hs, hsb, (B_ * S_ * HID_) / 4);
  cvt_kernel<<<14336, 256, 0, stream>>>(Wq, wqb, (DQ_ * HID_) / 4);
  cvt_kernel<<<7168,  256, 0, stream>>>(Wk, wkb, (DKV_ * HID_) / 4);
  cvt_kernel<<<7168,  256, 0, stream>>>(Wv, wvb, (DKV_ * HID_) / 4);
  cvt_kernel<<<14336, 256, 0, stream>>>(Wo, wob, (HID_ * DQ_) / 4);

  // 1) projections (bf16 x bf16, BK=64 global_load_lds staging, swizzled)
  gemm_lds<1><<<dim3(DQ_ / 128, M / 128), 256, 0, stream>>>(hsb, wqb, qb, M, DQ_, HID_, NH_);
  gemm_lds<1><<<dim3(DKV_ / 128, M / 128), 256, 0, stream>>>(hsb, wkb, kb, M, DKV_, HID_, NKV_);
  gemm_lds<2><<<dim3(DKV_ / 128, M / 128), 256, 0, stream>>>(hsb, wvb, vt, M, DKV_, HID_, NKV_);

  // 2) norm + rope (in place); K pass also stores per-row |k|^2
  normrope_kernel<4><<<(B_ * S_ * NH_) / 4, 256, 0, stream>>>(qb, qw, cosb, sinb, nullptr);
  normrope_kernel<3><<<(B_ * S_ * NKV_) / 4, 256, 0, stream>>>(kb, kw, cosb, sinb, knorm);
  kmax_reduce_kernel<<<B_ * NKV_, 256, 0, stream>>>(knorm, km);

  // 3) single-pass attention (p-tilde into weights buffer), XCD-pinned 1-D grid
  attn1p_kernel<<<(S_ / 64) * (B_ * NH_), 256, 0, stream>>>(qb, kb, vt, km, weights, linv, ctx);

  // 4) weights normalization + upper-triangle zeros
  wscale_kernel<<<(B_ * NH_ * S_) / 4, 256, 0, stream>>>(weights, linv);

  // 5) output projection -> d_out (f32)
  gemm_lds<0><<<dim3(HID_ / 128, M / 128), 256, 0, stream>>>(ctx, wob, attn_out, M, HID_, DQ_, 0);
}

// Round 15
// 985.995 us; speedup vs baseline: 2.3290x; 1.0042x over previous
//
#include <hip/hip_runtime.h>

// ---------------- problem constants ----------------
#define B_    2
#define S_    2048
#define HID_  3584
#define NH_   16
#define NKV_  8
#define HD_   256
#define DQ_   (NH_ * HD_)    // 4096
#define DKV_  (NKV_ * HD_)   // 2048

static constexpr float SCALE_ = 0.0625f;   // 256^-0.5

typedef __bf16 bf16_t;
typedef __bf16 bf16x8 __attribute__((ext_vector_type(8)));
typedef __bf16 bf16x4 __attribute__((ext_vector_type(4)));
typedef float  f32x4  __attribute__((ext_vector_type(4)));

// ---------------- f32 -> bf16 convert ----------------
__global__ __launch_bounds__(256) void cvt_kernel(const float* __restrict__ in,
                                                  bf16_t* __restrict__ out, int n4) {
  int i = blockIdx.x * 256 + threadIdx.x;
  if (i < n4) {
    float4 v = ((const float4*)in)[i];
    bf16x4 o;
    o[0] = (bf16_t)v.x; o[1] = (bf16_t)v.y; o[2] = (bf16_t)v.z; o[3] = (bf16_t)v.w;
    ((bf16x4*)out)[i] = o;
  }
}

// ---------------- async global->LDS, 16B per lane ----------------
__device__ inline void gload_lds16(const bf16_t* g, bf16_t* l) {
  __builtin_amdgcn_global_load_lds(
      (const __attribute__((address_space(1))) void*)g,
      (__attribute__((address_space(3))) void*)l, 16, 0, 0);
}

// ---------------- 256x256 8-wave pipelined GEMM: C[m][n] = sum_k A[m][k]*Bt[n][k] ----------------
// 512 thr = 2(M)x4(N) waves, each 128x64 C (acc[8][4]). BK=64, double-buffered 128KB LDS.
// 1-ahead prefetch: tile kt+1's 8 stage-sites issued across tile kt's 4 MFMA phases;
// single __syncthreads() per K-tile (its vmcnt drain == "next tile ready" -> race-free).
// Swizzle: source col unit ^= row&7 at staging, same XOR on ds_read (R14-proven involution).
// MODE 0: OUT f32 row-major [M][N]                      (o-proj -> d_out)
// MODE 1: OUT bf16 relayout (B, nh, S, HD)              (Q projection)
// MODE 3: combined KV: col<DKV -> K relayout into out;  col>=DKV -> V transpose into out2
template<int MODE>
__global__ __launch_bounds__(512, 1) void gemm256(const bf16_t* __restrict__ A,
                                                  const bf16_t* __restrict__ Bt,
                                                  void* __restrict__ outv,
                                                  void* __restrict__ out2v,
                                                  int M, int N, int K, int nh) {
  __shared__ __align__(16) bf16_t As[2][256 * 64];   // 64 KB
  __shared__ __align__(16) bf16_t Bs[2][256 * 64];   // 64 KB
  const int t = threadIdx.x;
  const int lane = t & 63, wv = t >> 6;
  const int wr = wv >> 2, wc = wv & 3;
  const int lr = lane & 15, lg = lane >> 4;
  const size_t m0 = (size_t)blockIdx.y * 256, n0 = (size_t)blockIdx.x * 256;

  // staging geometry: site = 64 rows x 64 cols; thread covers (row = wv*8 + lane>>3, unit = lane&7)
  const int srow = wv * 8 + (lane >> 3);
  const int scol = ((lane & 7) ^ ((lane >> 3) & 7)) * 8;   // pre-swizzled source col
  const bf16_t* ga = A  + (m0 + srow) * (size_t)K + scol;
  const bf16_t* gb = Bt + (n0 + srow) * (size_t)K + scol;
  const int ldso = wv * 512;   // wave-uniform LDS offset (elems); +lane*16B by HW

#define SITEA(rb, kc, pp) gload_lds16(ga + (size_t)(rb) * K + (kc), &As[pp][(rb) * 64 + ldso])
#define SITEB(rb, kc, pp) gload_lds16(gb + (size_t)(rb) * K + (kc), &Bs[pp][(rb) * 64 + ldso])

  const int NT = K >> 6;
  f32x4 acc[8][4] = {};
  bf16x8 af[4][2], bfr[2][2];

  // per-thread constant read offsets (swizzled)
  const int swz0 = ((0 + lg) ^ (lr & 7)) * 8;   // kk=0: unit = lg
  const int swz1 = ((4 + lg) ^ (lr & 7)) * 8;   // kk=1: unit = 4+lg
  const int aRB = (wr * 128 + lr) * 64;
  const int bRB = (wc * 64 + lr) * 64;

  // prologue: stage tile 0 into buffer 0
  SITEA(0, 0, 0); SITEA(64, 0, 0); SITEA(128, 0, 0); SITEA(192, 0, 0);
  SITEB(0, 0, 0); SITEB(64, 0, 0); SITEB(128, 0, 0); SITEB(192, 0, 0);

  for (int kt = 0; kt < NT; ++kt) {
    const int p = kt & 1, q = p ^ 1;
    __syncthreads();              // vmcnt+lgkm drain: buf[p] fully staged & visible
    const bool st = (kt + 1 < NT);
    const int kn = (kt + 1) << 6;

    // ---- phase 0: stage A rows 0-127 (next); read af i0-3 + bfr j0-1; MFMA q0 ----
    if (st) { SITEA(0, kn, q); SITEA(64, kn, q); }
#pragma unroll
    for (int i = 0; i < 4; ++i) {
      af[i][0] = *(const bf16x8*)&As[p][aRB + i * 1024 + swz0];
      af[i][1] = *(const bf16x8*)&As[p][aRB + i * 1024 + swz1];
    }
#pragma unroll
    for (int j = 0; j < 2; ++j) {
      bfr[j][0] = *(const bf16x8*)&Bs[p][bRB + j * 1024 + swz0];
      bfr[j][1] = *(const bf16x8*)&Bs[p][bRB + j * 1024 + swz1];
    }
#pragma unroll
    for (int i = 0; i < 4; ++i)
#pragma unroll
      for (int j = 0; j < 2; ++j) {
        acc[i][j] = __builtin_amdgcn_mfma_f32_16x16x32_bf16(af[i][0], bfr[j][0], acc[i][j], 0, 0, 0);
        acc[i][j] = __builtin_amdgcn_mfma_f32_16x16x32_bf16(af[i][1], bfr[j][1], acc[i][j], 0, 0, 0);
      }

    // ---- phase 1: stage A rows 128-255; read af i4-7; MFMA i4-7 x j0-1 ----
    if (st) { SITEA(128, kn, q); SITEA(192, kn, q); }
#pragma unroll
    for (int i = 0; i < 4; ++i) {
      af[i][0] = *(const bf16x8*)&As[p][aRB + (i + 4) * 1024 + swz0];
      af[i][1] = *(const bf16x8*)&As[p][aRB + (i + 4) * 1024 + swz1];
    }
#pragma unroll
    for (int i = 0; i < 4; ++i)
#pragma unroll
      for (int j = 0; j < 2; ++j) {
        acc[i + 4][j] = __builtin_amdgcn_mfma_f32_16x16x32_bf16(af[i][0], bfr[j][0], acc[i + 4][j], 0, 0, 0);
        acc[i + 4][j] = __builtin_amdgcn_mfma_f32_16x16x32_bf16(af[i][1], bfr[j][1], acc[i + 4][j], 0, 0, 0);
      }

    // ---- phase 2: stage B rows 0-127; read bfr j2-3; MFMA i4-7 x j2-3 ----
    if (st) { SITEB(0, kn, q); SITEB(64, kn, q); }
#pragma unroll
    for (int j = 0; j < 2; ++j) {
      bfr[j][0] = *(const bf16x8*)&Bs[p][bRB + (j + 2) * 1024 + swz0];
      bfr[j][1] = *(const bf16x8*)&Bs[p][bRB + (j + 2) * 1024 + swz1];
    }
#pragma unroll
    for (int i = 0; i < 4; ++i)
#pragma unroll
      for (int j = 0; j < 2; ++j) {
        acc[i + 4][j + 2] = __builtin_amdgcn_mfma_f32_16x16x32_bf16(af[i][0], bfr[j][0], acc[i + 4][j + 2], 0, 0, 0);
        acc[i + 4][j + 2] = __builtin_amdgcn_mfma_f32_16x16x32_bf16(af[i][1], bfr[j][1], acc[i + 4][j + 2], 0, 0, 0);
      }

    // ---- phase 3: stage B rows 128-255; read af i0-3; MFMA i0-3 x j2-3 ----
    if (st) { SITEB(128, kn, q); SITEB(192, kn, q); }
#pragma unroll
    for (int i = 0; i < 4; ++i) {
      af[i][0] = *(const bf16x8*)&As[p][aRB + i * 1024 + swz0];
      af[i][1] = *(const bf16x8*)&As[p][aRB + i * 1024 + swz1];
    }
#pragma unroll
    for (int i = 0; i < 4; ++i)
#pragma unroll
      for (int j = 0; j < 2; ++j) {
        acc[i][j + 2] = __builtin_amdgcn_mfma_f32_16x16x32_bf16(af[i][0], bfr[j][0], acc[i][j + 2], 0, 0, 0);
        acc[i][j + 2] = __builtin_amdgcn_mfma_f32_16x16x32_bf16(af[i][1], bfr[j][1], acc[i][j + 2], 0, 0, 0);
      }
  }
#undef SITEA
#undef SITEB

  // ---- epilogue: C/D layout col=lane&15, row=(lane>>4)*4+reg ----
#pragma unroll
  for (int i = 0; i < 8; ++i)
#pragma unroll
    for (int j = 0; j < 4; ++j) {
      const int row0 = (int)m0 + wr * 128 + i * 16 + lg * 4;
      const int col  = (int)n0 + wc * 64 + j * 16 + lr;
#pragma unroll
      for (int r = 0; r < 4; ++r) {
        const int row = row0 + r;
        if (MODE == 0) {
          ((float*)outv)[(size_t)row * N + col] = acc[i][j][r];
        } else {
          const bf16_t val = (bf16_t)acc[i][j][r];
          const int b = row >> 11, s = row & (S_ - 1);
          if (MODE == 1) {
            const int h = col >> 8, hd = col & (HD_ - 1);
            ((bf16_t*)outv)[((size_t)(b * nh + h) * S_ + s) * HD_ + hd] = val;
          } else {  // MODE 3: combined KV
            if (col < DKV_) {
              const int h = col >> 8, hd = col & (HD_ - 1);
              ((bf16_t*)outv)[((size_t)(b * NKV_ + h) * S_ + s) * HD_ + hd] = val;
            } else {
              const int c2 = col - DKV_;
              const int h = c2 >> 8, hd = c2 & (HD_ - 1);
              ((bf16_t*)out2v)[((size_t)(b * NKV_ + h) * HD_ + hd) * S_ + s] = val;
            }
          }
        }
      }
    }
}

// ---------------- fused RMSNorm + RoPE (in place), (b, s, h) block order ----------------
template<int LOGNH>
__global__ __launch_bounds__(256) void normrope_kernel(bf16_t* __restrict__ x,
                                                       const float* __restrict__ w,
                                                       const float* __restrict__ cosb,
                                                       const float* __restrict__ sinb,
                                                       float* __restrict__ rownorm) {
  const int gid  = blockIdx.x * 4 + (threadIdx.x >> 6);  // (b, s, h) order: h innermost
  const int lane = threadIdx.x & 63;
  const int nh = 1 << LOGNH;
  const int h  = gid & (nh - 1);
  const int bs = gid >> LOGNH;                 // b*S + s
  const int b  = bs >> 11, s = bs & (S_ - 1);
  const int rowi = (b * nh + h) * S_ + s;

  bf16_t* ptr = x + (size_t)rowi * HD_ + lane * 4;
  bf16x4 xv = *(const bf16x4*)ptr;
  float v0 = (float)xv[0], v1 = (float)xv[1], v2 = (float)xv[2], v3 = (float)xv[3];
  float ss = v0 * v0 + v1 * v1 + v2 * v2 + v3 * v3;
#pragma unroll
  for (int off = 1; off < 64; off <<= 1) ss += __shfl_xor(ss, off);
  float r = rsqrtf(ss * (1.0f / HD_) + 1e-6f);

  float4 wv = *(const float4*)(w + lane * 4);
  float x0 = v0 * r * (1.0f + wv.x);
  float x1 = v1 * r * (1.0f + wv.y);
  float x2 = v2 * r * (1.0f + wv.z);
  float x3 = v3 * r * (1.0f + wv.w);

  if (rownorm != nullptr) {   // row norm^2 after scale (RoPE preserves norm)
    float s2 = x0 * x0 + x1 * x1 + x2 * x2 + x3 * x3;
#pragma unroll
    for (int off = 1; off < 64; off <<= 1) s2 += __shfl_xor(s2, off);
    if (lane == 0) rownorm[rowi] = s2;
  }

  float p0 = __shfl_xor(x0, 32);
  float p1 = __shfl_xor(x1, 32);
  float p2 = __shfl_xor(x2, 32);
  float p3 = __shfl_xor(x3, 32);
  float sgn = (lane < 32) ? -1.0f : 1.0f;

  float4 c  = *(const float4*)(cosb + (size_t)bs * HD_ + lane * 4);
  float4 sn = *(const float4*)(sinb + (size_t)bs * HD_ + lane * 4);
  bf16x4 o;
  o[0] = (bf16_t)(x0 * c.x + sgn * p0 * sn.x);
  o[1] = (bf16_t)(x1 * c.y + sgn * p1 * sn.y);
  o[2] = (bf16_t)(x2 * c.z + sgn * p2 * sn.z);
  o[3] = (bf16_t)(x3 * c.w + sgn * p3 * sn.w);
  *(bf16x4*)ptr = o;
}

// ---------------- per-(b,kv-head) max of knorm ----------------
__global__ __launch_bounds__(256) void kmax_reduce_kernel(const float* __restrict__ knorm,
                                                          float* __restrict__ km) {
  __shared__ float red[4];
  const int t = threadIdx.x;
  const float* src = knorm + (size_t)blockIdx.x * S_;
  float m = 0.0f;
  for (int i = t; i < S_; i += 256) m = fmaxf(m, src[i]);
#pragma unroll
  for (int off = 1; off < 64; off <<= 1) m = fmaxf(m, __shfl_xor(m, off));
  if ((t & 63) == 0) red[t >> 6] = m;
  __syncthreads();
  if (t == 0) km[blockIdx.x] = fmaxf(fmaxf(red[0], red[1]), fmaxf(red[2], red[3]));
}

// ---------------- single-pass flash attention (XCD-pinned, LPT, coalesced p-stores) ----------------
__global__ __launch_bounds__(256) void attn1p_kernel(const bf16_t* __restrict__ qb,
                                                     const bf16_t* __restrict__ kb,
                                                     const bf16_t* __restrict__ vt,
                                                     const float* __restrict__ kmaxbuf,
                                                     float* __restrict__ wout,
                                                     float* __restrict__ linv,
                                                     bf16_t* __restrict__ ctx) {
  __shared__ __align__(16) bf16_t Ks[32][264];      // +8 pad
  __shared__ __align__(16) bf16_t Vs[256][40];      // d-major, +8 pad
  __shared__ __align__(16) bf16_t p_lds[4][16][40];
  __shared__ float qn_lds[4][16];

  const int t = threadIdx.x, w = t >> 6, lane = t & 63;
  const int lr = lane & 15, lg = lane >> 4, rloc = lg * 4;

  // XCD-pinned decode (wgid%8 = XCD round-robin); LPT: heavy q-buckets first
  const int wgid = blockIdx.x;
  const int g    = ((wgid >> 9) << 3) | (wgid & 7);   // (b*NKV + kvh) group, 0..15
  const int idx  = (wgid >> 3) & 63;
  const int b    = g >> 3, kvh = g & 7;
  const int h    = kvh * 2 + (idx >> 5);
  const int qbucket = 31 - (idx & 31);                // descending: longest first
  const int bh   = b * NH_ + h;
  const int q0b  = qbucket * 64;
  const int q0   = q0b + w * 16;

  const bf16_t* qptr = qb + ((size_t)bh * S_ + q0 + lr) * HD_ + lg * 8;
  bf16x8 qf[8];
#pragma unroll
  for (int c = 0; c < 8; ++c) qf[c] = *(const bf16x8*)(qptr + c * 32);

  float qn = 0.0f;
#pragma unroll
  for (int c = 0; c < 8; ++c)
#pragma unroll
    for (int e = 0; e < 8; ++e) { float v = (float)qf[c][e]; qn += v * v; }
  qn += __shfl_xor(qn, 16);
  qn += __shfl_xor(qn, 32);
  if (lg == 0) qn_lds[w][lr] = qn;
  __syncthreads();
  const float kmax2 = kmaxbuf[b * NKV_ + kvh];
  float mb[4];
#pragma unroll
  for (int r = 0; r < 4; ++r)
    mb[r] = SCALE_ * sqrtf(qn_lds[w][rloc + r] * kmax2) + 1.0f;  // >= any score, with margin

  float l[4] = {0.f, 0.f, 0.f, 0.f};
  f32x4 oacc[16] = {};
  const int nkt = (q0b + 64) >> 5;
  float* wrow = wout + ((size_t)bh * S_ + q0) * S_;
  const bf16_t* kgb = kb + (size_t)(b * NKV_ + kvh) * S_ * HD_;
  const bf16_t* vgb = vt + (size_t)(b * NKV_ + kvh) * HD_ * S_;

  const int s_st = t >> 3, c_st = (t & 7) * 32;   // K staging: row s_st, 4x8 cols
  const int vd   = t >> 3, vc   = (t & 7) * 4;    // V staging: rows vd+32i, 4 cols
  const int prow = lane >> 2, pcol = (lane & 3) * 8;  // p-tilde store geometry

  for (int kt = 0; kt < nkt; ++kt) {
    const int colb = kt * 32;
    __syncthreads();   // previous tile's LDS reads complete
    {  // stage K tile (32 x 256) coalesced
      const bf16_t* src = kgb + (size_t)(colb + s_st) * HD_ + c_st;
      bf16x8 k0 = *(const bf16x8*)(src);
      bf16x8 k1 = *(const bf16x8*)(src + 8);
      bf16x8 k2 = *(const bf16x8*)(src + 16);
      bf16x8 k3 = *(const bf16x8*)(src + 24);
      *(bf16x8*)&Ks[s_st][c_st]      = k0;
      *(bf16x8*)&Ks[s_st][c_st + 8]  = k1;
      *(bf16x8*)&Ks[s_st][c_st + 16] = k2;
      *(bf16x8*)&Ks[s_st][c_st + 24] = k3;
    }
#pragma unroll
    for (int i = 0; i < 8; ++i) {  // stage V tile (256 d x 32 s) from vt
      const int d = vd + i * 32;
      bf16x4 vv = *(const bf16x4*)(vgb + (size_t)d * S_ + colb + vc);
      *(bf16x4*)&Vs[d][vc] = vv;
    }
    __syncthreads();

    if (colb <= q0 + 15) {   // wave active for this tile
      f32x4 s0 = {0.f, 0.f, 0.f, 0.f}, s1 = {0.f, 0.f, 0.f, 0.f};
#pragma unroll
      for (int c = 0; c < 8; ++c) {
        bf16x8 k0 = *(const bf16x8*)&Ks[lr][c * 32 + lg * 8];
        bf16x8 k1 = *(const bf16x8*)&Ks[16 + lr][c * 32 + lg * 8];
        s0 = __builtin_amdgcn_mfma_f32_16x16x32_bf16(qf[c], k0, s0, 0, 0, 0);
        s1 = __builtin_amdgcn_mfma_f32_16x16x32_bf16(qf[c], k1, s1, 0, 0, 0);
      }
      const int col0 = colb + lr, col1 = col0 + 16;
#pragma unroll
      for (int r = 0; r < 4; ++r) {
        const int row = q0 + rloc + r;
        const float pa = (col0 <= row) ? __expf(s0[r] * SCALE_ - mb[r]) : 0.0f;
        const float pb = (col1 <= row) ? __expf(s1[r] * SCALE_ - mb[r]) : 0.0f;
        l[r] += pa + pb;
        p_lds[w][rloc + r][lr]      = (bf16_t)pa;
        p_lds[w][rloc + r][lr + 16] = (bf16_t)pb;
      }
      bf16x8 pf = *(const bf16x8*)&p_lds[w][lr][lg * 8];   // P as A-fragment
#pragma unroll
      for (int df = 0; df < 16; ++df) {
        bf16x8 vf = *(const bf16x8*)&Vs[df * 16 + lr][lg * 8];
        oacc[df] = __builtin_amdgcn_mfma_f32_16x16x32_bf16(pf, vf, oacc[df], 0, 0, 0);
      }
      // coalesced p-tilde store: lane covers row=lane>>2, 8 cols from (lane&3)*8
      {
        bf16x8 pv = *(const bf16x8*)&p_lds[w][prow][pcol];
        float* dst = wrow + (size_t)prow * S_ + colb + pcol;
        f32x4 lo = {(float)pv[0], (float)pv[1], (float)pv[2], (float)pv[3]};
        f32x4 hi = {(float)pv[4], (float)pv[5], (float)pv[6], (float)pv[7]};
        *(f32x4*)dst = lo;
        *(f32x4*)(dst + 4) = hi;
      }
    }
  }
  // row sum l across lr lanes
#pragma unroll
  for (int r = 0; r < 4; ++r) {
    l[r] += __shfl_xor(l[r], 1);
    l[r] += __shfl_xor(l[r], 2);
    l[r] += __shfl_xor(l[r], 4);
    l[r] += __shfl_xor(l[r], 8);
  }
  float invl[4];
#pragma unroll
  for (int r = 0; r < 4; ++r) invl[r] = 1.0f / l[r];

  bf16_t* cp = ctx + ((size_t)b * S_ + q0) * DQ_ + h * HD_;
#pragma unroll
  for (int df = 0; df < 16; ++df)
#pragma unroll
    for (int r = 0; r < 4; ++r)
      cp[(size_t)(rloc + r) * DQ_ + df * 16 + lr] = (bf16_t)(oacc[df][r] * invl[r]);

  if (lr == 0) {
#pragma unroll
    for (int r = 0; r < 4; ++r) linv[(size_t)bh * S_ + q0 + rloc + r] = invl[r];
  }
}

// ---------------- weights post-pass: scale lower triangle by 1/l, zero upper ----------------
__global__ __launch_bounds__(256) void wscale_kernel(float* __restrict__ wbuf,
                                                     const float* __restrict__ linv) {
  const int wv = threadIdx.x >> 6, lane = threadIdx.x & 63;
  const size_t rg = (size_t)blockIdx.x * 4 + wv;     // global row in (B*NH, S)
  const int row = (int)(rg & (S_ - 1));
  const float inv = linv[rg];
  float* base = wbuf + rg * S_;
#pragma unroll
  for (int i = 0; i < 8; ++i) {
    const int c0 = (i * 64 + lane) * 4;
    float4 v;
    if (c0 > row) {
      v = make_float4(0.f, 0.f, 0.f, 0.f);
    } else {
      v = *(const float4*)(base + c0);
      v.x = (c0 + 0 <= row) ? v.x * inv : 0.f;
      v.y = (c0 + 1 <= row) ? v.y * inv : 0.f;
      v.z = (c0 + 2 <= row) ? v.z * inv : 0.f;
      v.w = (c0 + 3 <= row) ? v.w * inv : 0.f;
    }
    *(float4*)(base + c0) = v;
  }
}

// ---------------- launch ----------------
extern "C" void kernel_launch(void* const* d_in, const int* in_sizes, int n_in,
                              void* d_out, int out_size, void* d_ws, size_t ws_size,
                              hipStream_t stream) {
  const float* hs   = (const float*)d_in[0];
  const float* cosb = (const float*)d_in[1];
  const float* sinb = (const float*)d_in[2];
  // d_in[3] attention_mask: recomputed causally in-kernel
  const float* Wq = (const float*)d_in[4];
  const float* Wk = (const float*)d_in[5];
  const float* Wv = (const float*)d_in[6];
  const float* Wo = (const float*)d_in[7];
  const float* qw = (const float*)d_in[8];
  const float* kw = (const float*)d_in[9];

  char* ws = (char*)d_ws;
  bf16_t* qb    = (bf16_t*)(ws + 0);            // 33,554,432  (B,NH,S,HD)
  bf16_t* kb    = (bf16_t*)(ws + 33554432);     // 16,777,216  (B,NKV,S,HD)
  bf16_t* vt    = (bf16_t*)(ws + 50331648);     // 16,777,216  (B,NKV,HD,S)
  bf16_t* ctx   = (bf16_t*)(ws + 67108864);     // 33,554,432  (B,S,NH*HD)
  float*  linv  = (float*)(ws + 100663296);     //    262,144
  float*  knorm = (float*)(ws + 100925440);     //    131,072
  float*  km    = (float*)(ws + 101056512);     //        128
  bf16_t* hsb   = (bf16_t*)(ws + 101056640);    // 29,360,128
  bf16_t* wqb   = (bf16_t*)(ws + 130416768);    // 29,360,128
  bf16_t* wkb   = (bf16_t*)(ws + 159776896);    // 14,680,064  (contiguous with wvb)
  bf16_t* wvb   = (bf16_t*)(ws + 174456960);    // 14,680,064
  bf16_t* wob   = (bf16_t*)(ws + 189137024);    // 29,360,128  -> total 218,497,152

  float* out      = (float*)d_out;
  float* attn_out = out;                            // (B,S,HID) f32
  float* weights  = out + (size_t)B_ * S_ * HID_;   // (B,NH,S,S) f32

  const int M = B_ * S_;  // 4096

  // 0) one-shot bf16 conversion of activations + weights
  cvt_kernel<<<14336, 256, 0, stream>>>(hs, hsb, (B_ * S_ * HID_) / 4);
  cvt_kernel<<<14336, 256, 0, stream>>>(Wq, wqb, (DQ_ * HID_) / 4);
  cvt_kernel<<<7168,  256, 0, stream>>>(Wk, wkb, (DKV_ * HID_) / 4);
  cvt_kernel<<<7168,  256, 0, stream>>>(Wv, wvb, (DKV_ * HID_) / 4);
  cvt_kernel<<<14336, 256, 0, stream>>>(Wo, wob, (HID_ * DQ_) / 4);

  // 1) projections: 256x256 pipelined GEMMs (Q; fused K+V via contiguous wkb|wvb)
  gemm256<1><<<dim3(DQ_ / 256, M / 256), 512, 0, stream>>>(hsb, wqb, qb, nullptr, M, DQ_, HID_, NH_);
  gemm256<3><<<dim3((2 * DKV_) / 256, M / 256), 512, 0, stream>>>(hsb, wkb, kb, vt, M, 2 * DKV_, HID_, NKV_);

  // 2) norm + rope (in place); K pass also stores per-row |k|^2
  normrope_kernel<4><<<(B_ * S_ * NH_) / 4, 256, 0, stream>>>(qb, qw, cosb, sinb, nullptr);
  normrope_kernel<3><<<(B_ * S_ * NKV_) / 4, 256, 0, stream>>>(kb, kw, cosb, sinb, knorm);
  kmax_reduce_kernel<<<B_ * NKV_, 256, 0, stream>>>(knorm, km);

  // 3) single-pass attention (p-tilde into weights buffer), XCD-pinned 1-D grid
  attn1p_kernel<<<(S_ / 64) * (B_ * NH_), 256, 0, stream>>>(qb, kb, vt, km, weights, linv, ctx);

  // 4) weights normalization + upper-triangle zeros
  wscale_kernel<<<(B_ * NH_ * S_) / 4, 256, 0, stream>>>(weights, linv);

  // 5) output projection -> d_out (f32)
  gemm256<0><<<dim3(HID_ / 256, M / 256), 512, 0, stream>>>(ctx, wob, attn_out, nullptr, M, HID_, DQ_, 0);
}

// Round 16
// 950.942 us; speedup vs baseline: 2.4149x; 1.0369x over previous
//
#include <hip/hip_runtime.h>

// ---------------- problem constants ----------------
#define B_    2
#define S_    2048
#define HID_  3584
#define NH_   16
#define NKV_  8
#define HD_   256
#define DQ_   (NH_ * HD_)    // 4096
#define DKV_  (NKV_ * HD_)   // 2048

static constexpr float SCALE_ = 0.0625f;   // 256^-0.5

typedef __bf16 bf16_t;
typedef __bf16 bf16x8 __attribute__((ext_vector_type(8)));
typedef __bf16 bf16x4 __attribute__((ext_vector_type(4)));
typedef float  f32x4  __attribute__((ext_vector_type(4)));

// ---------------- f32 -> bf16 convert ----------------
__global__ __launch_bounds__(256) void cvt_kernel(const float* __restrict__ in,
                                                  bf16_t* __restrict__ out, int n4) {
  int i = blockIdx.x * 256 + threadIdx.x;
  if (i < n4) {
    float4 v = ((const float4*)in)[i];
    bf16x4 o;
    o[0] = (bf16_t)v.x; o[1] = (bf16_t)v.y; o[2] = (bf16_t)v.z; o[3] = (bf16_t)v.w;
    ((bf16x4*)out)[i] = o;
  }
}

// ---------------- async global->LDS, 16B per lane ----------------
__device__ inline void gload_lds16(const bf16_t* g, bf16_t* l) {
  __builtin_amdgcn_global_load_lds(
      (const __attribute__((address_space(1))) void*)g,
      (__attribute__((address_space(3))) void*)l, 16, 0, 0);
}

// ---------------- 256x256 8-wave pipelined GEMM: C[m][n] = sum_k A[m][k]*Bt[n][k] ----------------
// 512 thr = 2(M)x4(N) waves, each 128x64 C (acc[8][4]). BK=64, double-buffered 128KB LDS.
// 1-ahead prefetch spread across 4 MFMA phases; single __syncthreads() per K-tile.
// Swizzle: source col unit ^= row&7 at staging, same XOR on ds_read (involution).
// MODE 0: OUT f32 row-major [M][N]; MODE 1: bf16 relayout (B,nh,S,HD);
// MODE 3: combined KV: col<DKV -> K relayout; col>=DKV -> V transpose into out2
template<int MODE>
__global__ __launch_bounds__(512, 1) void gemm256(const bf16_t* __restrict__ A,
                                                  const bf16_t* __restrict__ Bt,
                                                  void* __restrict__ outv,
                                                  void* __restrict__ out2v,
                                                  int M, int N, int K, int nh) {
  __shared__ __align__(16) bf16_t As[2][256 * 64];   // 64 KB
  __shared__ __align__(16) bf16_t Bs[2][256 * 64];   // 64 KB
  const int t = threadIdx.x;
  const int lane = t & 63, wv = t >> 6;
  const int wr = wv >> 2, wc = wv & 3;
  const int lr = lane & 15, lg = lane >> 4;
  const size_t m0 = (size_t)blockIdx.y * 256, n0 = (size_t)blockIdx.x * 256;

  const int srow = wv * 8 + (lane >> 3);
  const int scol = ((lane & 7) ^ ((lane >> 3) & 7)) * 8;   // pre-swizzled source col
  const bf16_t* ga = A  + (m0 + srow) * (size_t)K + scol;
  const bf16_t* gb = Bt + (n0 + srow) * (size_t)K + scol;
  const int ldso = wv * 512;   // wave-uniform LDS offset (elems)

#define SITEA(rb, kc, pp) gload_lds16(ga + (size_t)(rb) * K + (kc), &As[pp][(rb) * 64 + ldso])
#define SITEB(rb, kc, pp) gload_lds16(gb + (size_t)(rb) * K + (kc), &Bs[pp][(rb) * 64 + ldso])

  const int NT = K >> 6;
  f32x4 acc[8][4] = {};
  bf16x8 af[4][2], bfr[2][2];

  const int swz0 = ((0 + lg) ^ (lr & 7)) * 8;
  const int swz1 = ((4 + lg) ^ (lr & 7)) * 8;
  const int aRB = (wr * 128 + lr) * 64;
  const int bRB = (wc * 64 + lr) * 64;

  SITEA(0, 0, 0); SITEA(64, 0, 0); SITEA(128, 0, 0); SITEA(192, 0, 0);
  SITEB(0, 0, 0); SITEB(64, 0, 0); SITEB(128, 0, 0); SITEB(192, 0, 0);

  for (int kt = 0; kt < NT; ++kt) {
    const int p = kt & 1, q = p ^ 1;
    __syncthreads();
    const bool st = (kt + 1 < NT);
    const int kn = (kt + 1) << 6;

    if (st) { SITEA(0, kn, q); SITEA(64, kn, q); }
#pragma unroll
    for (int i = 0; i < 4; ++i) {
      af[i][0] = *(const bf16x8*)&As[p][aRB + i * 1024 + swz0];
      af[i][1] = *(const bf16x8*)&As[p][aRB + i * 1024 + swz1];
    }
#pragma unroll
    for (int j = 0; j < 2; ++j) {
      bfr[j][0] = *(const bf16x8*)&Bs[p][bRB + j * 1024 + swz0];
      bfr[j][1] = *(const bf16x8*)&Bs[p][bRB + j * 1024 + swz1];
    }
#pragma unroll
    for (int i = 0; i < 4; ++i)
#pragma unroll
      for (int j = 0; j < 2; ++j) {
        acc[i][j] = __builtin_amdgcn_mfma_f32_16x16x32_bf16(af[i][0], bfr[j][0], acc[i][j], 0, 0, 0);
        acc[i][j] = __builtin_amdgcn_mfma_f32_16x16x32_bf16(af[i][1], bfr[j][1], acc[i][j], 0, 0, 0);
      }

    if (st) { SITEA(128, kn, q); SITEA(192, kn, q); }
#pragma unroll
    for (int i = 0; i < 4; ++i) {
      af[i][0] = *(const bf16x8*)&As[p][aRB + (i + 4) * 1024 + swz0];
      af[i][1] = *(const bf16x8*)&As[p][aRB + (i + 4) * 1024 + swz1];
    }
#pragma unroll
    for (int i = 0; i < 4; ++i)
#pragma unroll
      for (int j = 0; j < 2; ++j) {
        acc[i + 4][j] = __builtin_amdgcn_mfma_f32_16x16x32_bf16(af[i][0], bfr[j][0], acc[i + 4][j], 0, 0, 0);
        acc[i + 4][j] = __builtin_amdgcn_mfma_f32_16x16x32_bf16(af[i][1], bfr[j][1], acc[i + 4][j], 0, 0, 0);
      }

    if (st) { SITEB(0, kn, q); SITEB(64, kn, q); }
#pragma unroll
    for (int j = 0; j < 2; ++j) {
      bfr[j][0] = *(const bf16x8*)&Bs[p][bRB + (j + 2) * 1024 + swz0];
      bfr[j][1] = *(const bf16x8*)&Bs[p][bRB + (j + 2) * 1024 + swz1];
    }
#pragma unroll
    for (int i = 0; i < 4; ++i)
#pragma unroll
      for (int j = 0; j < 2; ++j) {
        acc[i + 4][j + 2] = __builtin_amdgcn_mfma_f32_16x16x32_bf16(af[i][0], bfr[j][0], acc[i + 4][j + 2], 0, 0, 0);
        acc[i + 4][j + 2] = __builtin_amdgcn_mfma_f32_16x16x32_bf16(af[i][1], bfr[j][1], acc[i + 4][j + 2], 0, 0, 0);
      }

    if (st) { SITEB(128, kn, q); SITEB(192, kn, q); }
#pragma unroll
    for (int i = 0; i < 4; ++i) {
      af[i][0] = *(const bf16x8*)&As[p][aRB + i * 1024 + swz0];
      af[i][1] = *(const bf16x8*)&As[p][aRB + i * 1024 + swz1];
    }
#pragma unroll
    for (int i = 0; i < 4; ++i)
#pragma unroll
      for (int j = 0; j < 2; ++j) {
        acc[i][j + 2] = __builtin_amdgcn_mfma_f32_16x16x32_bf16(af[i][0], bfr[j][0], acc[i][j + 2], 0, 0, 0);
        acc[i][j + 2] = __builtin_amdgcn_mfma_f32_16x16x32_bf16(af[i][1], bfr[j][1], acc[i][j + 2], 0, 0, 0);
      }
  }
#undef SITEA
#undef SITEB

#pragma unroll
  for (int i = 0; i < 8; ++i)
#pragma unroll
    for (int j = 0; j < 4; ++j) {
      const int row0 = (int)m0 + wr * 128 + i * 16 + lg * 4;
      const int col  = (int)n0 + wc * 64 + j * 16 + lr;
#pragma unroll
      for (int r = 0; r < 4; ++r) {
        const int row = row0 + r;
        if (MODE == 0) {
          ((float*)outv)[(size_t)row * N + col] = acc[i][j][r];
        } else {
          const bf16_t val = (bf16_t)acc[i][j][r];
          const int b = row >> 11, s = row & (S_ - 1);
          if (MODE == 1) {
            const int h = col >> 8, hd = col & (HD_ - 1);
            ((bf16_t*)outv)[((size_t)(b * nh + h) * S_ + s) * HD_ + hd] = val;
          } else {  // MODE 3: combined KV
            if (col < DKV_) {
              const int h = col >> 8, hd = col & (HD_ - 1);
              ((bf16_t*)outv)[((size_t)(b * NKV_ + h) * S_ + s) * HD_ + hd] = val;
            } else {
              const int c2 = col - DKV_;
              const int h = c2 >> 8, hd = c2 & (HD_ - 1);
              ((bf16_t*)out2v)[((size_t)(b * NKV_ + h) * HD_ + hd) * S_ + s] = val;
            }
          }
        }
      }
    }
}

// ---------------- fused RMSNorm + RoPE (in place), (b, s, h) block order ----------------
template<int LOGNH>
__global__ __launch_bounds__(256) void normrope_kernel(bf16_t* __restrict__ x,
                                                       const float* __restrict__ w,
                                                       const float* __restrict__ cosb,
                                                       const float* __restrict__ sinb,
                                                       float* __restrict__ rownorm) {
  const int gid  = blockIdx.x * 4 + (threadIdx.x >> 6);  // (b, s, h) order: h innermost
  const int lane = threadIdx.x & 63;
  const int nh = 1 << LOGNH;
  const int h  = gid & (nh - 1);
  const int bs = gid >> LOGNH;                 // b*S + s
  const int b  = bs >> 11, s = bs & (S_ - 1);
  const int rowi = (b * nh + h) * S_ + s;

  bf16_t* ptr = x + (size_t)rowi * HD_ + lane * 4;
  bf16x4 xv = *(const bf16x4*)ptr;
  float v0 = (float)xv[0], v1 = (float)xv[1], v2 = (float)xv[2], v3 = (float)xv[3];
  float ss = v0 * v0 + v1 * v1 + v2 * v2 + v3 * v3;
#pragma unroll
  for (int off = 1; off < 64; off <<= 1) ss += __shfl_xor(ss, off);
  float r = rsqrtf(ss * (1.0f / HD_) + 1e-6f);

  float4 wv = *(const float4*)(w + lane * 4);
  float x0 = v0 * r * (1.0f + wv.x);
  float x1 = v1 * r * (1.0f + wv.y);
  float x2 = v2 * r * (1.0f + wv.z);
  float x3 = v3 * r * (1.0f + wv.w);

  if (rownorm != nullptr) {   // row norm^2 after scale (RoPE preserves norm)
    float s2 = x0 * x0 + x1 * x1 + x2 * x2 + x3 * x3;
#pragma unroll
    for (int off = 1; off < 64; off <<= 1) s2 += __shfl_xor(s2, off);
    if (lane == 0) rownorm[rowi] = s2;
  }

  float p0 = __shfl_xor(x0, 32);
  float p1 = __shfl_xor(x1, 32);
  float p2 = __shfl_xor(x2, 32);
  float p3 = __shfl_xor(x3, 32);
  float sgn = (lane < 32) ? -1.0f : 1.0f;

  float4 c  = *(const float4*)(cosb + (size_t)bs * HD_ + lane * 4);
  float4 sn = *(const float4*)(sinb + (size_t)bs * HD_ + lane * 4);
  bf16x4 o;
  o[0] = (bf16_t)(x0 * c.x + sgn * p0 * sn.x);
  o[1] = (bf16_t)(x1 * c.y + sgn * p1 * sn.y);
  o[2] = (bf16_t)(x2 * c.z + sgn * p2 * sn.z);
  o[3] = (bf16_t)(x3 * c.w + sgn * p3 * sn.w);
  *(bf16x4*)ptr = o;
}

// ---------------- per-(b,kv-head) max of knorm ----------------
__global__ __launch_bounds__(256) void kmax_reduce_kernel(const float* __restrict__ knorm,
                                                          float* __restrict__ km) {
  __shared__ float red[4];
  const int t = threadIdx.x;
  const float* src = knorm + (size_t)blockIdx.x * S_;
  float m = 0.0f;
  for (int i = t; i < S_; i += 256) m = fmaxf(m, src[i]);
#pragma unroll
  for (int off = 1; off < 64; off <<= 1) m = fmaxf(m, __shfl_xor(m, off));
  if ((t & 63) == 0) red[t >> 6] = m;
  __syncthreads();
  if (t == 0) km[blockIdx.x] = fmaxf(fmaxf(red[0], red[1]), fmaxf(red[2], red[3]));
}

// ---------------- single-pass flash attention (XCD-pinned, LPT) ----------------
// p-tilde stored as bf16 (16B/lane coalesced) into pt scratch; LDS pads trimmed to 36
// (40,192 B -> 4 blocks/CU). Weights = f32(bf16(p)) * invl, bit-identical to prior rounds.
__global__ __launch_bounds__(256) void attn1p_kernel(const bf16_t* __restrict__ qb,
                                                     const bf16_t* __restrict__ kb,
                                                     const bf16_t* __restrict__ vt,
                                                     const float* __restrict__ kmaxbuf,
                                                     bf16_t* __restrict__ pt,
                                                     float* __restrict__ linv,
                                                     bf16_t* __restrict__ ctx) {
  __shared__ __align__(16) bf16_t Ks[32][264];      // +8 pad
  __shared__ __align__(16) bf16_t Vs[256][36];      // d-major, +4 pad
  __shared__ __align__(16) bf16_t p_lds[4][16][36];
  __shared__ float qn_lds[4][16];

  const int t = threadIdx.x, w = t >> 6, lane = t & 63;
  const int lr = lane & 15, lg = lane >> 4, rloc = lg * 4;

  // XCD-pinned decode (wgid%8 = XCD round-robin); LPT: heavy q-buckets first
  const int wgid = blockIdx.x;
  const int g    = ((wgid >> 9) << 3) | (wgid & 7);   // (b*NKV + kvh) group, 0..15
  const int idx  = (wgid >> 3) & 63;
  const int b    = g >> 3, kvh = g & 7;
  const int h    = kvh * 2 + (idx >> 5);
  const int qbucket = 31 - (idx & 31);                // descending: longest first
  const int bh   = b * NH_ + h;
  const int q0b  = qbucket * 64;
  const int q0   = q0b + w * 16;

  const bf16_t* qptr = qb + ((size_t)bh * S_ + q0 + lr) * HD_ + lg * 8;
  bf16x8 qf[8];
#pragma unroll
  for (int c = 0; c < 8; ++c) qf[c] = *(const bf16x8*)(qptr + c * 32);

  float qn = 0.0f;
#pragma unroll
  for (int c = 0; c < 8; ++c)
#pragma unroll
    for (int e = 0; e < 8; ++e) { float v = (float)qf[c][e]; qn += v * v; }
  qn += __shfl_xor(qn, 16);
  qn += __shfl_xor(qn, 32);
  if (lg == 0) qn_lds[w][lr] = qn;
  __syncthreads();
  const float kmax2 = kmaxbuf[b * NKV_ + kvh];
  float mb[4];
#pragma unroll
  for (int r = 0; r < 4; ++r)
    mb[r] = SCALE_ * sqrtf(qn_lds[w][rloc + r] * kmax2) + 1.0f;  // >= any score, with margin

  float l[4] = {0.f, 0.f, 0.f, 0.f};
  f32x4 oacc[16] = {};
  const int nkt = (q0b + 64) >> 5;
  bf16_t* prow_g = pt + ((size_t)bh * S_ + q0) * S_;
  const bf16_t* kgb = kb + (size_t)(b * NKV_ + kvh) * S_ * HD_;
  const bf16_t* vgb = vt + (size_t)(b * NKV_ + kvh) * HD_ * S_;

  const int s_st = t >> 3, c_st = (t & 7) * 32;   // K staging: row s_st, 4x8 cols
  const int vd   = t >> 3, vc   = (t & 7) * 4;    // V staging: rows vd+32i, 4 cols
  const int prow = lane >> 2, pcol = (lane & 3) * 8;  // p-tilde store geometry

  for (int kt = 0; kt < nkt; ++kt) {
    const int colb = kt * 32;
    __syncthreads();   // previous tile's LDS reads complete
    {  // stage K tile (32 x 256) coalesced
      const bf16_t* src = kgb + (size_t)(colb + s_st) * HD_ + c_st;
      bf16x8 k0 = *(const bf16x8*)(src);
      bf16x8 k1 = *(const bf16x8*)(src + 8);
      bf16x8 k2 = *(const bf16x8*)(src + 16);
      bf16x8 k3 = *(const bf16x8*)(src + 24);
      *(bf16x8*)&Ks[s_st][c_st]      = k0;
      *(bf16x8*)&Ks[s_st][c_st + 8]  = k1;
      *(bf16x8*)&Ks[s_st][c_st + 16] = k2;
      *(bf16x8*)&Ks[s_st][c_st + 24] = k3;
    }
#pragma unroll
    for (int i = 0; i < 8; ++i) {  // stage V tile (256 d x 32 s) from vt
      const int d = vd + i * 32;
      bf16x4 vv = *(const bf16x4*)(vgb + (size_t)d * S_ + colb + vc);
      *(bf16x4*)&Vs[d][vc] = vv;
    }
    __syncthreads();

    if (colb <= q0 + 15) {   // wave active for this tile
      f32x4 s0 = {0.f, 0.f, 0.f, 0.f}, s1 = {0.f, 0.f, 0.f, 0.f};
#pragma unroll
      for (int c = 0; c < 8; ++c) {
        bf16x8 k0 = *(const bf16x8*)&Ks[lr][c * 32 + lg * 8];
        bf16x8 k1 = *(const bf16x8*)&Ks[16 + lr][c * 32 + lg * 8];
        s0 = __builtin_amdgcn_mfma_f32_16x16x32_bf16(qf[c], k0, s0, 0, 0, 0);
        s1 = __builtin_amdgcn_mfma_f32_16x16x32_bf16(qf[c], k1, s1, 0, 0, 0);
      }
      const int col0 = colb + lr, col1 = col0 + 16;
#pragma unroll
      for (int r = 0; r < 4; ++r) {
        const int row = q0 + rloc + r;
        const float pa = (col0 <= row) ? __expf(s0[r] * SCALE_ - mb[r]) : 0.0f;
        const float pb = (col1 <= row) ? __expf(s1[r] * SCALE_ - mb[r]) : 0.0f;
        l[r] += pa + pb;
        p_lds[w][rloc + r][lr]      = (bf16_t)pa;
        p_lds[w][rloc + r][lr + 16] = (bf16_t)pb;
      }
      bf16x8 pf = *(const bf16x8*)&p_lds[w][lr][lg * 8];   // P as A-fragment
#pragma unroll
      for (int df = 0; df < 16; ++df) {
        bf16x8 vf = *(const bf16x8*)&Vs[df * 16 + lr][lg * 8];
        oacc[df] = __builtin_amdgcn_mfma_f32_16x16x32_bf16(pf, vf, oacc[df], 0, 0, 0);
      }
      // coalesced bf16 p-tilde store: lane covers row=lane>>2, 8 cols from (lane&3)*8
      {
        bf16x8 pv = *(const bf16x8*)&p_lds[w][prow][pcol];
        *(bf16x8*)(prow_g + (size_t)prow * S_ + colb + pcol) = pv;
      }
    }
  }
  // row sum l across lr lanes
#pragma unroll
  for (int r = 0; r < 4; ++r) {
    l[r] += __shfl_xor(l[r], 1);
    l[r] += __shfl_xor(l[r], 2);
    l[r] += __shfl_xor(l[r], 4);
    l[r] += __shfl_xor(l[r], 8);
  }
  float invl[4];
#pragma unroll
  for (int r = 0; r < 4; ++r) invl[r] = 1.0f / l[r];

  bf16_t* cp = ctx + ((size_t)b * S_ + q0) * DQ_ + h * HD_;
#pragma unroll
  for (int df = 0; df < 16; ++df)
#pragma unroll
    for (int r = 0; r < 4; ++r)
      cp[(size_t)(rloc + r) * DQ_ + df * 16 + lr] = (bf16_t)(oacc[df][r] * invl[r]);

  if (lr == 0) {
#pragma unroll
    for (int r = 0; r < 4; ++r) linv[(size_t)bh * S_ + q0 + rloc + r] = invl[r];
  }
}

// ---------------- weights finalize: read bf16 p-tilde, write normalized f32 + zeros ----------------
__global__ __launch_bounds__(256) void wscale_kernel(float* __restrict__ wbuf,
                                                     const bf16_t* __restrict__ pt,
                                                     const float* __restrict__ linv) {
  const int wv = threadIdx.x >> 6, lane = threadIdx.x & 63;
  const size_t rg = (size_t)blockIdx.x * 4 + wv;     // global row in (B*NH, S)
  const int row = (int)(rg & (S_ - 1));
  const float inv = linv[rg];
  const bf16_t* src = pt + rg * S_;
  float* base = wbuf + rg * S_;
#pragma unroll
  for (int i = 0; i < 8; ++i) {
    const int c0 = (i * 64 + lane) * 4;
    float4 v;
    if (c0 > row) {
      v = make_float4(0.f, 0.f, 0.f, 0.f);
    } else {
      bf16x4 bv = *(const bf16x4*)(src + c0);
      v.x = (c0 + 0 <= row) ? (float)bv[0] * inv : 0.f;
      v.y = (c0 + 1 <= row) ? (float)bv[1] * inv : 0.f;
      v.z = (c0 + 2 <= row) ? (float)bv[2] * inv : 0.f;
      v.w = (c0 + 3 <= row) ? (float)bv[3] * inv : 0.f;
    }
    *(float4*)(base + c0) = v;
  }
}

// ---------------- launch ----------------
extern "C" void kernel_launch(void* const* d_in, const int* in_sizes, int n_in,
                              void* d_out, int out_size, void* d_ws, size_t ws_size,
                              hipStream_t stream) {
  const float* hs   = (const float*)d_in[0];
  const float* cosb = (const float*)d_in[1];
  const float* sinb = (const float*)d_in[2];
  // d_in[3] attention_mask: recomputed causally in-kernel
  const float* Wq = (const float*)d_in[4];
  const float* Wk = (const float*)d_in[5];
  const float* Wv = (const float*)d_in[6];
  const float* Wo = (const float*)d_in[7];
  const float* qw = (const float*)d_in[8];
  const float* kw = (const float*)d_in[9];

  char* ws = (char*)d_ws;
  bf16_t* qb    = (bf16_t*)(ws + 0);            // 33,554,432  (B,NH,S,HD)
  bf16_t* kb    = (bf16_t*)(ws + 33554432);     // 16,777,216  (B,NKV,S,HD)
  bf16_t* vt    = (bf16_t*)(ws + 50331648);     // 16,777,216  (B,NKV,HD,S)
  bf16_t* ctx   = (bf16_t*)(ws + 67108864);     // 33,554,432  (B,S,NH*HD)
  float*  linv  = (float*)(ws + 100663296);     //    262,144
  float*  knorm = (float*)(ws + 100925440);     //    131,072
  float*  km    = (float*)(ws + 101056512);     //        128
  bf16_t* hsb   = (bf16_t*)(ws + 101056640);    // 29,360,128
  bf16_t* wqb   = (bf16_t*)(ws + 130416768);    // 29,360,128
  bf16_t* wkb   = (bf16_t*)(ws + 159776896);    // 14,680,064  (contiguous with wvb)
  bf16_t* wvb   = (bf16_t*)(ws + 174456960);    // 14,680,064
  bf16_t* wob   = (bf16_t*)(ws + 189137024);    // 29,360,128
  bf16_t* pt    = (bf16_t*)(ws + 218497152);    // 268,435,456 (B,NH,S,S) bf16 -> total 486,932,608

  float* out      = (float*)d_out;
  float* attn_out = out;                            // (B,S,HID) f32
  float* weights  = out + (size_t)B_ * S_ * HID_;   // (B,NH,S,S) f32

  const int M = B_ * S_;  // 4096

  // 0) one-shot bf16 conversion of activations + weights
  cvt_kernel<<<14336, 256, 0, stream>>>(hs, hsb, (B_ * S_ * HID_) / 4);
  cvt_kernel<<<14336, 256, 0, stream>>>(Wq, wqb, (DQ_ * HID_) / 4);
  cvt_kernel<<<7168,  256, 0, stream>>>(Wk, wkb, (DKV_ * HID_) / 4);
  cvt_kernel<<<7168,  256, 0, stream>>>(Wv, wvb, (DKV_ * HID_) / 4);
  cvt_kernel<<<14336, 256, 0, stream>>>(Wo, wob, (HID_ * DQ_) / 4);

  // 1) projections: 256x256 pipelined GEMMs (Q; fused K+V via contiguous wkb|wvb)
  gemm256<1><<<dim3(DQ_ / 256, M / 256), 512, 0, stream>>>(hsb, wqb, qb, nullptr, M, DQ_, HID_, NH_);
  gemm256<3><<<dim3((2 * DKV_) / 256, M / 256), 512, 0, stream>>>(hsb, wkb, kb, vt, M, 2 * DKV_, HID_, NKV_);

  // 2) norm + rope (in place); K pass also stores per-row |k|^2
  normrope_kernel<4><<<(B_ * S_ * NH_) / 4, 256, 0, stream>>>(qb, qw, cosb, sinb, nullptr);
  normrope_kernel<3><<<(B_ * S_ * NKV_) / 4, 256, 0, stream>>>(kb, kw, cosb, sinb, knorm);
  kmax_reduce_kernel<<<B_ * NKV_, 256, 0, stream>>>(knorm, km);

  // 3) single-pass attention (bf16 p-tilde into pt scratch), XCD-pinned 1-D grid
  attn1p_kernel<<<(S_ / 64) * (B_ * NH_), 256, 0, stream>>>(qb, kb, vt, km, pt, linv, ctx);

  // 4) weights finalize: bf16 p-tilde -> normalized f32 + upper-triangle zeros
  wscale_kernel<<<(B_ * NH_ * S_) / 4, 256, 0, stream>>>(weights, pt, linv);

  // 5) output projection -> d_out (f32)
  gemm256<0><<<dim3(HID_ / 256, M / 256), 512, 0, stream>>>(ctx, wob, attn_out, nullptr, M, HID_, DQ_, 0);
}

// Round 17
// 869.954 us; speedup vs baseline: 2.6397x; 1.0931x over previous
//
#include <hip/hip_runtime.h>

// ---------------- problem constants ----------------
#define B_    2
#define S_    2048
#define HID_  3584
#define NH_   16
#define NKV_  8
#define HD_   256
#define DQ_   (NH_ * HD_)    // 4096
#define DKV_  (NKV_ * HD_)   // 2048

static constexpr float SCALE_ = 0.0625f;   // 256^-0.5

typedef __bf16 bf16_t;
typedef __bf16 bf16x8 __attribute__((ext_vector_type(8)));
typedef __bf16 bf16x4 __attribute__((ext_vector_type(4)));
typedef float  f32x4  __attribute__((ext_vector_type(4)));

// ---------------- f32 -> bf16 convert ----------------
__global__ __launch_bounds__(256) void cvt_kernel(const float* __restrict__ in,
                                                  bf16_t* __restrict__ out, int n4) {
  int i = blockIdx.x * 256 + threadIdx.x;
  if (i < n4) {
    float4 v = ((const float4*)in)[i];
    bf16x4 o;
    o[0] = (bf16_t)v.x; o[1] = (bf16_t)v.y; o[2] = (bf16_t)v.z; o[3] = (bf16_t)v.w;
    ((bf16x4*)out)[i] = o;
  }
}

// ---------------- async global->LDS, 16B per lane ----------------
__device__ inline void gload_lds16(const bf16_t* g, bf16_t* l) {
  __builtin_amdgcn_global_load_lds(
      (const __attribute__((address_space(1))) void*)g,
      (__attribute__((address_space(3))) void*)l, 16, 0, 0);
}

// ---------------- 256x256 8-wave pipelined GEMM: C[m][n] = sum_k A[m][k]*Bt[n][k] ----------------
// 512 thr = 2(M)x4(N) waves, each 128x64 C (acc[8][4]). BK=64, double-buffered 128KB LDS.
// 1-ahead prefetch, ALL 8 sites issued right after the barrier (full-tile latency window);
// single __syncthreads() per K-tile. Swizzle: source col unit ^= row&7; same XOR on ds_read.
// MODE 0: OUT f32 row-major [M][N]; MODE 1: bf16 relayout (B,nh,S,HD);
// MODE 3: combined KV: col<DKV -> K relayout; col>=DKV -> V transpose into out2
template<int MODE>
__global__ __launch_bounds__(512, 1) void gemm256(const bf16_t* __restrict__ A,
                                                  const bf16_t* __restrict__ Bt,
                                                  void* __restrict__ outv,
                                                  void* __restrict__ out2v,
                                                  int M, int N, int K, int nh) {
  __shared__ __align__(16) bf16_t As[2][256 * 64];   // 64 KB
  __shared__ __align__(16) bf16_t Bs[2][256 * 64];   // 64 KB
  const int t = threadIdx.x;
  const int lane = t & 63, wv = t >> 6;
  const int wr = wv >> 2, wc = wv & 3;
  const int lr = lane & 15, lg = lane >> 4;
  const size_t m0 = (size_t)blockIdx.y * 256, n0 = (size_t)blockIdx.x * 256;

  const int srow = wv * 8 + (lane >> 3);
  const int scol = ((lane & 7) ^ ((lane >> 3) & 7)) * 8;   // pre-swizzled source col
  const bf16_t* ga = A  + (m0 + srow) * (size_t)K + scol;
  const bf16_t* gb = Bt + (n0 + srow) * (size_t)K + scol;
  const int ldso = wv * 512;   // wave-uniform LDS offset (elems)

#define SITEA(rb, kc, pp) gload_lds16(ga + (size_t)(rb) * K + (kc), &As[pp][(rb) * 64 + ldso])
#define SITEB(rb, kc, pp) gload_lds16(gb + (size_t)(rb) * K + (kc), &Bs[pp][(rb) * 64 + ldso])

  const int NT = K >> 6;
  f32x4 acc[8][4] = {};
  bf16x8 af[4][2], bfr[2][2];

  const int swz0 = ((0 + lg) ^ (lr & 7)) * 8;
  const int swz1 = ((4 + lg) ^ (lr & 7)) * 8;
  const int aRB = (wr * 128 + lr) * 64;
  const int bRB = (wc * 64 + lr) * 64;

  SITEA(0, 0, 0); SITEA(64, 0, 0); SITEA(128, 0, 0); SITEA(192, 0, 0);
  SITEB(0, 0, 0); SITEB(64, 0, 0); SITEB(128, 0, 0); SITEB(192, 0, 0);

  for (int kt = 0; kt < NT; ++kt) {
    const int p = kt & 1, q = p ^ 1;
    __syncthreads();              // vmcnt drain: buf[p] staged & visible
    // ---- issue ALL next-tile loads up front: full tile of compute hides them ----
    if (kt + 1 < NT) {
      const int kn = (kt + 1) << 6;
      SITEA(0, kn, q); SITEA(64, kn, q); SITEA(128, kn, q); SITEA(192, kn, q);
      SITEB(0, kn, q); SITEB(64, kn, q); SITEB(128, kn, q); SITEB(192, kn, q);
    }

    // ---- phase 0: quadrant i0-3 x j0-1 ----
#pragma unroll
    for (int i = 0; i < 4; ++i) {
      af[i][0] = *(const bf16x8*)&As[p][aRB + i * 1024 + swz0];
      af[i][1] = *(const bf16x8*)&As[p][aRB + i * 1024 + swz1];
    }
#pragma unroll
    for (int j = 0; j < 2; ++j) {
      bfr[j][0] = *(const bf16x8*)&Bs[p][bRB + j * 1024 + swz0];
      bfr[j][1] = *(const bf16x8*)&Bs[p][bRB + j * 1024 + swz1];
    }
#pragma unroll
    for (int i = 0; i < 4; ++i)
#pragma unroll
      for (int j = 0; j < 2; ++j) {
        acc[i][j] = __builtin_amdgcn_mfma_f32_16x16x32_bf16(af[i][0], bfr[j][0], acc[i][j], 0, 0, 0);
        acc[i][j] = __builtin_amdgcn_mfma_f32_16x16x32_bf16(af[i][1], bfr[j][1], acc[i][j], 0, 0, 0);
      }

    // ---- phase 1: quadrant i4-7 x j0-1 ----
#pragma unroll
    for (int i = 0; i < 4; ++i) {
      af[i][0] = *(const bf16x8*)&As[p][aRB + (i + 4) * 1024 + swz0];
      af[i][1] = *(const bf16x8*)&As[p][aRB + (i + 4) * 1024 + swz1];
    }
#pragma unroll
    for (int i = 0; i < 4; ++i)
#pragma unroll
      for (int j = 0; j < 2; ++j) {
        acc[i + 4][j] = __builtin_amdgcn_mfma_f32_16x16x32_bf16(af[i][0], bfr[j][0], acc[i + 4][j], 0, 0, 0);
        acc[i + 4][j] = __builtin_amdgcn_mfma_f32_16x16x32_bf16(af[i][1], bfr[j][1], acc[i + 4][j], 0, 0, 0);
      }

    // ---- phase 2: quadrant i4-7 x j2-3 ----
#pragma unroll
    for (int j = 0; j < 2; ++j) {
      bfr[j][0] = *(const bf16x8*)&Bs[p][bRB + (j + 2) * 1024 + swz0];
      bfr[j][1] = *(const bf16x8*)&Bs[p][bRB + (j + 2) * 1024 + swz1];
    }
#pragma unroll
    for (int i = 0; i < 4; ++i)
#pragma unroll
      for (int j = 0; j < 2; ++j) {
        acc[i + 4][j + 2] = __builtin_amdgcn_mfma_f32_16x16x32_bf16(af[i][0], bfr[j][0], acc[i + 4][j + 2], 0, 0, 0);
        acc[i + 4][j + 2] = __builtin_amdgcn_mfma_f32_16x16x32_bf16(af[i][1], bfr[j][1], acc[i + 4][j + 2], 0, 0, 0);
      }

    // ---- phase 3: quadrant i0-3 x j2-3 ----
#pragma unroll
    for (int i = 0; i < 4; ++i) {
      af[i][0] = *(const bf16x8*)&As[p][aRB + i * 1024 + swz0];
      af[i][1] = *(const bf16x8*)&As[p][aRB + i * 1024 + swz1];
    }
#pragma unroll
    for (int i = 0; i < 4; ++i)
#pragma unroll
      for (int j = 0; j < 2; ++j) {
        acc[i][j + 2] = __builtin_amdgcn_mfma_f32_16x16x32_bf16(af[i][0], bfr[j][0], acc[i][j + 2], 0, 0, 0);
        acc[i][j + 2] = __builtin_amdgcn_mfma_f32_16x16x32_bf16(af[i][1], bfr[j][1], acc[i][j + 2], 0, 0, 0);
      }
  }
#undef SITEA
#undef SITEB

#pragma unroll
  for (int i = 0; i < 8; ++i)
#pragma unroll
    for (int j = 0; j < 4; ++j) {
      const int row0 = (int)m0 + wr * 128 + i * 16 + lg * 4;
      const int col  = (int)n0 + wc * 64 + j * 16 + lr;
#pragma unroll
      for (int r = 0; r < 4; ++r) {
        const int row = row0 + r;
        if (MODE == 0) {
          ((float*)outv)[(size_t)row * N + col] = acc[i][j][r];
        } else {
          const bf16_t val = (bf16_t)acc[i][j][r];
          const int b = row >> 11, s = row & (S_ - 1);
          if (MODE == 1) {
            const int h = col >> 8, hd = col & (HD_ - 1);
            ((bf16_t*)outv)[((size_t)(b * nh + h) * S_ + s) * HD_ + hd] = val;
          } else {  // MODE 3: combined KV
            if (col < DKV_) {
              const int h = col >> 8, hd = col & (HD_ - 1);
              ((bf16_t*)outv)[((size_t)(b * NKV_ + h) * S_ + s) * HD_ + hd] = val;
            } else {
              const int c2 = col - DKV_;
              const int h = c2 >> 8, hd = c2 & (HD_ - 1);
              ((bf16_t*)out2v)[((size_t)(b * NKV_ + h) * HD_ + hd) * S_ + s] = val;
            }
          }
        }
      }
    }
}

// ---------------- fused RMSNorm + RoPE (in place), (b, s, h) block order ----------------
template<int LOGNH>
__global__ __launch_bounds__(256) void normrope_kernel(bf16_t* __restrict__ x,
                                                       const float* __restrict__ w,
                                                       const float* __restrict__ cosb,
                                                       const float* __restrict__ sinb,
                                                       float* __restrict__ rownorm) {
  const int gid  = blockIdx.x * 4 + (threadIdx.x >> 6);  // (b, s, h) order: h innermost
  const int lane = threadIdx.x & 63;
  const int nh = 1 << LOGNH;
  const int h  = gid & (nh - 1);
  const int bs = gid >> LOGNH;                 // b*S + s
  const int b  = bs >> 11, s = bs & (S_ - 1);
  const int rowi = (b * nh + h) * S_ + s;

  bf16_t* ptr = x + (size_t)rowi * HD_ + lane * 4;
  bf16x4 xv = *(const bf16x4*)ptr;
  float v0 = (float)xv[0], v1 = (float)xv[1], v2 = (float)xv[2], v3 = (float)xv[3];
  float ss = v0 * v0 + v1 * v1 + v2 * v2 + v3 * v3;
#pragma unroll
  for (int off = 1; off < 64; off <<= 1) ss += __shfl_xor(ss, off);
  float r = rsqrtf(ss * (1.0f / HD_) + 1e-6f);

  float4 wv = *(const float4*)(w + lane * 4);
  float x0 = v0 * r * (1.0f + wv.x);
  float x1 = v1 * r * (1.0f + wv.y);
  float x2 = v2 * r * (1.0f + wv.z);
  float x3 = v3 * r * (1.0f + wv.w);

  if (rownorm != nullptr) {   // row norm^2 after scale (RoPE preserves norm)
    float s2 = x0 * x0 + x1 * x1 + x2 * x2 + x3 * x3;
#pragma unroll
    for (int off = 1; off < 64; off <<= 1) s2 += __shfl_xor(s2, off);
    if (lane == 0) rownorm[rowi] = s2;
  }

  float p0 = __shfl_xor(x0, 32);
  float p1 = __shfl_xor(x1, 32);
  float p2 = __shfl_xor(x2, 32);
  float p3 = __shfl_xor(x3, 32);
  float sgn = (lane < 32) ? -1.0f : 1.0f;

  float4 c  = *(const float4*)(cosb + (size_t)bs * HD_ + lane * 4);
  float4 sn = *(const float4*)(sinb + (size_t)bs * HD_ + lane * 4);
  bf16x4 o;
  o[0] = (bf16_t)(x0 * c.x + sgn * p0 * sn.x);
  o[1] = (bf16_t)(x1 * c.y + sgn * p1 * sn.y);
  o[2] = (bf16_t)(x2 * c.z + sgn * p2 * sn.z);
  o[3] = (bf16_t)(x3 * c.w + sgn * p3 * sn.w);
  *(bf16x4*)ptr = o;
}

// ---------------- per-(b,kv-head) max of knorm ----------------
__global__ __launch_bounds__(256) void kmax_reduce_kernel(const float* __restrict__ knorm,
                                                          float* __restrict__ km) {
  __shared__ float red[4];
  const int t = threadIdx.x;
  const float* src = knorm + (size_t)blockIdx.x * S_;
  float m = 0.0f;
  for (int i = t; i < S_; i += 256) m = fmaxf(m, src[i]);
#pragma unroll
  for (int off = 1; off < 64; off <<= 1) m = fmaxf(m, __shfl_xor(m, off));
  if ((t & 63) == 0) red[t >> 6] = m;
  __syncthreads();
  if (t == 0) km[blockIdx.x] = fmaxf(fmaxf(red[0], red[1]), fmaxf(red[2], red[3]));
}

// ---------------- single-pass flash attention (XCD-pinned, LPT, T14 reg-prefetch) ----------------
// Next tile's K/V loaded into registers during current tile's compute (no launch_bounds clamp
// this time — R9/R10's regression was the VGPR 64 clamp, not the prefetch).
__global__ __launch_bounds__(256) void attn1p_kernel(const bf16_t* __restrict__ qb,
                                                     const bf16_t* __restrict__ kb,
                                                     const bf16_t* __restrict__ vt,
                                                     const float* __restrict__ kmaxbuf,
                                                     bf16_t* __restrict__ pt,
                                                     float* __restrict__ linv,
                                                     bf16_t* __restrict__ ctx) {
  __shared__ __align__(16) bf16_t Ks[32][264];      // +8 pad
  __shared__ __align__(16) bf16_t Vs[256][36];      // d-major, +4 pad
  __shared__ __align__(16) bf16_t p_lds[4][16][36];
  __shared__ float qn_lds[4][16];

  const int t = threadIdx.x, w = t >> 6, lane = t & 63;
  const int lr = lane & 15, lg = lane >> 4, rloc = lg * 4;

  // XCD-pinned decode (wgid%8 = XCD round-robin); LPT: heavy q-buckets first
  const int wgid = blockIdx.x;
  const int g    = ((wgid >> 9) << 3) | (wgid & 7);   // (b*NKV + kvh) group, 0..15
  const int idx  = (wgid >> 3) & 63;
  const int b    = g >> 3, kvh = g & 7;
  const int h    = kvh * 2 + (idx >> 5);
  const int qbucket = 31 - (idx & 31);                // descending: longest first
  const int bh   = b * NH_ + h;
  const int q0b  = qbucket * 64;
  const int q0   = q0b + w * 16;

  const bf16_t* qptr = qb + ((size_t)bh * S_ + q0 + lr) * HD_ + lg * 8;
  bf16x8 qf[8];
#pragma unroll
  for (int c = 0; c < 8; ++c) qf[c] = *(const bf16x8*)(qptr + c * 32);

  float qn = 0.0f;
#pragma unroll
  for (int c = 0; c < 8; ++c)
#pragma unroll
    for (int e = 0; e < 8; ++e) { float v = (float)qf[c][e]; qn += v * v; }
  qn += __shfl_xor(qn, 16);
  qn += __shfl_xor(qn, 32);
  if (lg == 0) qn_lds[w][lr] = qn;
  __syncthreads();
  const float kmax2 = kmaxbuf[b * NKV_ + kvh];
  float mb[4];
#pragma unroll
  for (int r = 0; r < 4; ++r)
    mb[r] = SCALE_ * sqrtf(qn_lds[w][rloc + r] * kmax2) + 1.0f;  // >= any score, with margin

  float l[4] = {0.f, 0.f, 0.f, 0.f};
  f32x4 oacc[16] = {};
  const int nkt = (q0b + 64) >> 5;
  bf16_t* prow_g = pt + ((size_t)bh * S_ + q0) * S_;
  const bf16_t* kgb = kb + (size_t)(b * NKV_ + kvh) * S_ * HD_;
  const bf16_t* vgb = vt + (size_t)(b * NKV_ + kvh) * HD_ * S_;

  const int s_st = t >> 3, c_st = (t & 7) * 32;   // K staging: row s_st, 4x8 cols
  const int vd   = t >> 3, vc   = (t & 7) * 4;    // V staging: rows vd+32i, 4 cols
  const int prow = lane >> 2, pcol = (lane & 3) * 8;  // p-tilde store geometry

  // ---- prefetch tile 0 into registers ----
  bf16x8 kreg0, kreg1, kreg2, kreg3;
  bf16x4 vreg[8];
  {
    const bf16_t* src = kgb + (size_t)s_st * HD_ + c_st;
    kreg0 = *(const bf16x8*)(src);
    kreg1 = *(const bf16x8*)(src + 8);
    kreg2 = *(const bf16x8*)(src + 16);
    kreg3 = *(const bf16x8*)(src + 24);
#pragma unroll
    for (int i = 0; i < 8; ++i)
      vreg[i] = *(const bf16x4*)(vgb + (size_t)(vd + i * 32) * S_ + vc);
  }

  for (int kt = 0; kt < nkt; ++kt) {
    const int colb = kt * 32;
    __syncthreads();   // previous tile's LDS reads complete
    *(bf16x8*)&Ks[s_st][c_st]      = kreg0;
    *(bf16x8*)&Ks[s_st][c_st + 8]  = kreg1;
    *(bf16x8*)&Ks[s_st][c_st + 16] = kreg2;
    *(bf16x8*)&Ks[s_st][c_st + 24] = kreg3;
#pragma unroll
    for (int i = 0; i < 8; ++i) *(bf16x4*)&Vs[vd + i * 32][vc] = vreg[i];
    __syncthreads();

    if (kt + 1 < nkt) {   // T14: issue next tile's loads; latency hides under compute
      const int nb = colb + 32;
      const bf16_t* src = kgb + (size_t)(nb + s_st) * HD_ + c_st;
      kreg0 = *(const bf16x8*)(src);
      kreg1 = *(const bf16x8*)(src + 8);
      kreg2 = *(const bf16x8*)(src + 16);
      kreg3 = *(const bf16x8*)(src + 24);
#pragma unroll
      for (int i = 0; i < 8; ++i)
        vreg[i] = *(const bf16x4*)(vgb + (size_t)(vd + i * 32) * S_ + nb + vc);
    }

    if (colb <= q0 + 15) {   // wave active for this tile
      f32x4 s0 = {0.f, 0.f, 0.f, 0.f}, s1 = {0.f, 0.f, 0.f, 0.f};
#pragma unroll
      for (int c = 0; c < 8; ++c) {
        bf16x8 k0 = *(const bf16x8*)&Ks[lr][c * 32 + lg * 8];
        bf16x8 k1 = *(const bf16x8*)&Ks[16 + lr][c * 32 + lg * 8];
        s0 = __builtin_amdgcn_mfma_f32_16x16x32_bf16(qf[c], k0, s0, 0, 0, 0);
        s1 = __builtin_amdgcn_mfma_f32_16x16x32_bf16(qf[c], k1, s1, 0, 0, 0);
      }
      const int col0 = colb + lr, col1 = col0 + 16;
#pragma unroll
      for (int r = 0; r < 4; ++r) {
        const int row = q0 + rloc + r;
        const float pa = (col0 <= row) ? __expf(s0[r] * SCALE_ - mb[r]) : 0.0f;
        const float pb = (col1 <= row) ? __expf(s1[r] * SCALE_ - mb[r]) : 0.0f;
        l[r] += pa + pb;
        p_lds[w][rloc + r][lr]      = (bf16_t)pa;
        p_lds[w][rloc + r][lr + 16] = (bf16_t)pb;
      }
      bf16x8 pf = *(const bf16x8*)&p_lds[w][lr][lg * 8];   // P as A-fragment
#pragma unroll
      for (int df = 0; df < 16; ++df) {
        bf16x8 vf = *(const bf16x8*)&Vs[df * 16 + lr][lg * 8];
        oacc[df] = __builtin_amdgcn_mfma_f32_16x16x32_bf16(pf, vf, oacc[df], 0, 0, 0);
      }
      // coalesced bf16 p-tilde store: lane covers row=lane>>2, 8 cols from (lane&3)*8
      {
        bf16x8 pv = *(const bf16x8*)&p_lds[w][prow][pcol];
        *(bf16x8*)(prow_g + (size_t)prow * S_ + colb + pcol) = pv;
      }
    }
  }
  // row sum l across lr lanes
#pragma unroll
  for (int r = 0; r < 4; ++r) {
    l[r] += __shfl_xor(l[r], 1);
    l[r] += __shfl_xor(l[r], 2);
    l[r] += __shfl_xor(l[r], 4);
    l[r] += __shfl_xor(l[r], 8);
  }
  float invl[4];
#pragma unroll
  for (int r = 0; r < 4; ++r) invl[r] = 1.0f / l[r];

  bf16_t* cp = ctx + ((size_t)b * S_ + q0) * DQ_ + h * HD_;
#pragma unroll
  for (int df = 0; df < 16; ++df)
#pragma unroll
    for (int r = 0; r < 4; ++r)
      cp[(size_t)(rloc + r) * DQ_ + df * 16 + lr] = (bf16_t)(oacc[df][r] * invl[r]);

  if (lr == 0) {
#pragma unroll
    for (int r = 0; r < 4; ++r) linv[(size_t)bh * S_ + q0 + rloc + r] = invl[r];
  }
}

// ---------------- weights finalize: read bf16 p-tilde, write normalized f32 + zeros ----------------
__global__ __launch_bounds__(256) void wscale_kernel(float* __restrict__ wbuf,
                                                     const bf16_t* __restrict__ pt,
                                                     const float* __restrict__ linv) {
  const int wv = threadIdx.x >> 6, lane = threadIdx.x & 63;
  const size_t rg = (size_t)blockIdx.x * 4 + wv;     // global row in (B*NH, S)
  const int row = (int)(rg & (S_ - 1));
  const float inv = linv[rg];
  const bf16_t* src = pt + rg * S_;
  float* base = wbuf + rg * S_;
#pragma unroll
  for (int i = 0; i < 8; ++i) {
    const int c0 = (i * 64 + lane) * 4;
    float4 v;
    if (c0 > row) {
      v = make_float4(0.f, 0.f, 0.f, 0.f);
    } else {
      bf16x4 bv = *(const bf16x4*)(src + c0);
      v.x = (c0 + 0 <= row) ? (float)bv[0] * inv : 0.f;
      v.y = (c0 + 1 <= row) ? (float)bv[1] * inv : 0.f;
      v.z = (c0 + 2 <= row) ? (float)bv[2] * inv : 0.f;
      v.w = (c0 + 3 <= row) ? (float)bv[3] * inv : 0.f;
    }
    *(float4*)(base + c0) = v;
  }
}

// ---------------- launch ----------------
extern "C" void kernel_launch(void* const* d_in, const int* in_sizes, int n_in,
                              void* d_out, int out_size, void* d_ws, size_t ws_size,
                              hipStream_t stream) {
  const float* hs   = (const float*)d_in[0];
  const float* cosb = (const float*)d_in[1];
  const float* sinb = (const float*)d_in[2];
  // d_in[3] attention_mask: recomputed causally in-kernel
  const float* Wq = (const float*)d_in[4];
  const float* Wk = (const float*)d_in[5];
  const float* Wv = (const float*)d_in[6];
  const float* Wo = (const float*)d_in[7];
  const float* qw = (const float*)d_in[8];
  const float* kw = (const float*)d_in[9];

  char* ws = (char*)d_ws;
  bf16_t* qb    = (bf16_t*)(ws + 0);            // 33,554,432  (B,NH,S,HD)
  bf16_t* kb    = (bf16_t*)(ws + 33554432);     // 16,777,216  (B,NKV,S,HD)
  bf16_t* vt    = (bf16_t*)(ws + 50331648);     // 16,777,216  (B,NKV,HD,S)
  bf16_t* ctx   = (bf16_t*)(ws + 67108864);     // 33,554,432  (B,S,NH*HD)
  float*  linv  = (float*)(ws + 100663296);     //    262,144
  float*  knorm = (float*)(ws + 100925440);     //    131,072
  float*  km    = (float*)(ws + 101056512);     //        128
  bf16_t* hsb   = (bf16_t*)(ws + 101056640);    // 29,360,128
  bf16_t* wqb   = (bf16_t*)(ws + 130416768);    // 29,360,128
  bf16_t* wkb   = (bf16_t*)(ws + 159776896);    // 14,680,064  (contiguous with wvb)
  bf16_t* wvb   = (bf16_t*)(ws + 174456960);    // 14,680,064
  bf16_t* wob   = (bf16_t*)(ws + 189137024);    // 29,360,128
  bf16_t* pt    = (bf16_t*)(ws + 218497152);    // 268,435,456 (B,NH,S,S) bf16 -> total 486,932,608

  float* out      = (float*)d_out;
  float* attn_out = out;                            // (B,S,HID) f32
  float* weights  = out + (size_t)B_ * S_ * HID_;   // (B,NH,S,S) f32

  const int M = B_ * S_;  // 4096

  // 0) one-shot bf16 conversion of activations + weights
  cvt_kernel<<<14336, 256, 0, stream>>>(hs, hsb, (B_ * S_ * HID_) / 4);
  cvt_kernel<<<14336, 256, 0, stream>>>(Wq, wqb, (DQ_ * HID_) / 4);
  cvt_kernel<<<7168,  256, 0, stream>>>(Wk, wkb, (DKV_ * HID_) / 4);
  cvt_kernel<<<7168,  256, 0, stream>>>(Wv, wvb, (DKV_ * HID_) / 4);
  cvt_kernel<<<14336, 256, 0, stream>>>(Wo, wob, (HID_ * DQ_) / 4);

  // 1) projections: 256x256 pipelined GEMMs (Q; fused K+V via contiguous wkb|wvb)
  gemm256<1><<<dim3(DQ_ / 256, M / 256), 512, 0, stream>>>(hsb, wqb, qb, nullptr, M, DQ_, HID_, NH_);
  gemm256<3><<<dim3((2 * DKV_) / 256, M / 256), 512, 0, stream>>>(hsb, wkb, kb, vt, M, 2 * DKV_, HID_, NKV_);

  // 2) norm + rope (in place); K pass also stores per-row |k|^2
  normrope_kernel<4><<<(B_ * S_ * NH_) / 4, 256, 0, stream>>>(qb, qw, cosb, sinb, nullptr);
  normrope_kernel<3><<<(B_ * S_ * NKV_) / 4, 256, 0, stream>>>(kb, kw, cosb, sinb, knorm);
  kmax_reduce_kernel<<<B_ * NKV_, 256, 0, stream>>>(knorm, km);

  // 3) single-pass attention (bf16 p-tilde into pt scratch), XCD-pinned 1-D grid
  attn1p_kernel<<<(S_ / 64) * (B_ * NH_), 256, 0, stream>>>(qb, kb, vt, km, pt, linv, ctx);

  // 4) weights finalize: bf16 p-tilde -> normalized f32 + upper-triangle zeros
  wscale_kernel<<<(B_ * NH_ * S_) / 4, 256, 0, stream>>>(weights, pt, linv);

  // 5) output projection -> d_out (f32)
  gemm256<0><<<dim3(HID_ / 256, M / 256), 512, 0, stream>>>(ctx, wob, attn_out, nullptr, M, HID_, DQ_, 0);
}